// Round 15
// baseline (5449.147 us; speedup 1.0000x reference)
//
#include <hip/hip_runtime.h>
#include <hip/hip_bf16.h>
#include <math.h>

typedef __hip_bfloat16 bf16;
typedef __bf16 bf16x8 __attribute__((ext_vector_type(8)));
typedef float  f32x4  __attribute__((ext_vector_type(4)));
typedef unsigned long long u64;

#define T_SEQ 256
#define BATCH 64
#define FEATD 188
#define HID   512
#define EMB   1024
#define NTAG  14
#define G3    1536   // 3*HID
#define GRU_NBLK 32  // 16 blocks/dir x 32 hidden cols

// ---------------------------------------------------------------------------
// fp32 -> bf16 weight conversion (vectorized x4; all n % 4 == 0)
// ---------------------------------------------------------------------------
__global__ __launch_bounds__(256) void f32_to_bf16(
    const float* __restrict__ src, bf16* __restrict__ dst, int n4)
{
  int i = blockIdx.x * 256 + threadIdx.x;
  if (i >= n4) return;
  float4 v = *(const float4*)(src + (size_t)i * 4);
  bf16 o[4] = {__float2bfloat16(v.x), __float2bfloat16(v.y),
               __float2bfloat16(v.z), __float2bfloat16(v.w)};
  *(ushort4*)(dst + (size_t)i * 4) = *(ushort4*)o;
}

// ---------------------------------------------------------------------------
// MFMA GEMM: C[M,N] = concat(A1,A2)[M,K] @ W[N,K]^T + bias. (validated R3)
// ---------------------------------------------------------------------------
__global__ __launch_bounds__(256) void gemm_mfma(
    const bf16* __restrict__ A1, int lda1,
    const bf16* __restrict__ A2, int lda2, int K1,
    const bf16* __restrict__ W, int ldw,
    const float* __restrict__ bias,
    bf16* __restrict__ C, int ldc,
    int M, int N, int K)
{
  __shared__ __bf16 As[128][40];
  __shared__ __bf16 Bs[128][40];
  const int bm = blockIdx.y * 128;
  const int bn = blockIdx.x * 128;
  const int tid = threadIdx.x;
  const int wave = tid >> 6, lane = tid & 63;
  const int wr = wave >> 1, wc = wave & 1;
  const int lr = lane & 15, lk = (lane >> 4) << 3;
  f32x4 acc[4][4] = {};
  for (int k0 = 0; k0 < K; k0 += 32) {
#pragma unroll
    for (int p = 0; p < 4; ++p) {
      int i = tid + p * 256;
      int row = i >> 3, q = i & 7;
      int kg = k0 + q * 4;
      ushort4 va{0, 0, 0, 0}, vb{0, 0, 0, 0};
      if (kg < K) {
        const bf16* srca = (kg < K1) ? A1 + (size_t)(bm + row) * lda1 + kg
                                     : A2 + (size_t)(bm + row) * lda2 + (kg - K1);
        va = *(const ushort4*)srca;
        vb = *(const ushort4*)(W + (size_t)(bn + row) * ldw + kg);
      }
      *(ushort4*)&As[row][q * 4] = va;
      *(ushort4*)&Bs[row][q * 4] = vb;
    }
    __syncthreads();
    bf16x8 af[4], bf_[4];
#pragma unroll
    for (int i = 0; i < 4; ++i)
      af[i] = *(const bf16x8*)&As[wr * 64 + i * 16 + lr][lk];
#pragma unroll
    for (int j = 0; j < 4; ++j)
      bf_[j] = *(const bf16x8*)&Bs[wc * 64 + j * 16 + lr][lk];
#pragma unroll
    for (int i = 0; i < 4; ++i)
#pragma unroll
      for (int j = 0; j < 4; ++j)
        acc[i][j] = __builtin_amdgcn_mfma_f32_16x16x32_bf16(af[i], bf_[j], acc[i][j], 0, 0, 0);
    __syncthreads();
  }
#pragma unroll
  for (int j = 0; j < 4; ++j) {
    int n = bn + wc * 64 + j * 16 + lr;
    float bv = bias ? bias[n] : 0.f;
#pragma unroll
    for (int i = 0; i < 4; ++i) {
#pragma unroll
      for (int p = 0; p < 4; ++p) {
        int m = bm + wr * 64 + i * 16 + (lane >> 4) * 4 + p;
        C[(size_t)m * ldc + n] = __float2bfloat16(acc[i][j][p] + bv);
      }
    }
  }
}

// ---------------------------------------------------------------------------
// features [B,T,FEAT] fp32 -> xT [T,B,FEAT] bf16
// ---------------------------------------------------------------------------
__global__ __launch_bounds__(256) void transpose_feat(
    const float* __restrict__ f, bf16* __restrict__ xT)
{
  const int idx = blockIdx.x * 256 + threadIdx.x;
  const int total = BATCH * T_SEQ * FEATD;
  if (idx >= total) return;
  const int i = idx % FEATD;
  const int r = idx / FEATD;
  const int b = r / T_SEQ;
  const int t = r % T_SEQ;
  xT[((size_t)t * BATCH + b) * FEATD + i] = __float2bfloat16(f[idx]);
}

// ---------------------------------------------------------------------------
// Persistent bidirectional GRU layer, v11 = R14 per-wave chains + data-as-flag.
// 32 blocks (dir x 16 col-tiles of 32 cols), 256 threads = 4 waves.
// Each wave owns a disjoint 16-batch-row slice: chain (dir,wave) independent.
// out[] pre-poisoned to 0x7F bytes; |h| <= 1 so a real bf16 h never has top
// byte 0x7F. Consumer wave retry-loads its 32 batched u64 h-values until no
// u32 half carries the poison byte -> the h-load IS the poll (1 IF RTT
// instead of flag-RTT + load-RTT). Producer: gates -> packed u32 agent
// stores -> wave-level vmcnt(0) drain (bounds visibility) -> xp prefetch.
// ZERO __syncthreads and ZERO flag traffic in the loop.
// ---------------------------------------------------------------------------
__global__ __launch_bounds__(256, 1) void gru_persist(
    const bf16* __restrict__ xp_f, const bf16* __restrict__ xp_b,
    const bf16* __restrict__ whh_f, const bf16* __restrict__ whh_b,
    const float* __restrict__ bhh_f, const float* __restrict__ bhh_b,
    bf16* __restrict__ out)
{
  const int blk = blockIdx.x;
  const int dir = blk >> 4;
  const int ct  = blk & 15;
  const bf16* xp   = dir ? xp_b  : xp_f;
  const bf16* whh  = dir ? whh_b : whh_f;
  const float* bhh = dir ? bhh_b : bhh_f;
  const int off = dir ? HID : 0;
  const int tid = threadIdx.x;
  const int wave = tid >> 6, lane = tid & 63;
  const int lr = lane & 15, lkq = lane >> 4;

  // weights: rows r = g*32 + n, padded stride 520 (1040 B, 16B-aligned).
  // Read-only after init -> safe to share across drifting waves.
  __shared__ __bf16 Ws[96][520];
  for (int i = tid; i < 96 * 64; i += 256) {
    int r = i >> 6, q = i & 63;
    int grow = (r >> 5) * HID + ct * 32 + (r & 31);
    *(float4*)&Ws[r][q * 8] = *(const float4*)(whh + (size_t)grow * HID + q * 8);
  }
  __syncthreads();   // ONLY block-wide sync; before the loop.

  float bh[3][2];
#pragma unroll
  for (int g = 0; g < 3; ++g)
#pragma unroll
    for (int nf = 0; nf < 2; ++nf)
      bh[g][nf] = bhh[g * HID + ct * 32 + nf * 16 + lr];

  float hp[2][4] = {};   // own h state (rows wave*16+lkq*4+p, cols nf*16+lr)

  // xp in registers, prologue for step 0
  bf16 xc[3][2][4];
  {
    const int t0 = dir ? (T_SEQ - 1) : 0;
    const size_t xb = (size_t)t0 * BATCH * G3;
#pragma unroll
    for (int p = 0; p < 4; ++p) {
      const size_t xrow = xb + (size_t)(wave * 16 + lkq * 4 + p) * G3;
#pragma unroll
      for (int g = 0; g < 3; ++g)
#pragma unroll
        for (int nf = 0; nf < 2; ++nf)
          xc[g][nf][p] = xp[xrow + g * HID + ct * 32 + nf * 16 + lr];
    }
  }

  for (int s = 0; s < T_SEQ; ++s) {
    const int t = dir ? (T_SEQ - 1 - s) : s;

    f32x4 acc[3][2] = {};
    if (s > 0) {
      // ---- retry-load h(t_prev): 32 coalesced agent u64 loads; the load
      //      doubles as the readiness poll (poison byte 0x7F). Wave-local.
      const int tp = dir ? t + 1 : t - 1;
      const bf16* arow = out + (size_t)tp * BATCH * EMB + off
                         + (size_t)(wave * 16 + lr) * EMB + lkq * 8;
      u64 h0[16], h1[16];
      unsigned bad;
      do {
#pragma unroll
        for (int ki = 0; ki < 16; ++ki) {
          h0[ki] = __hip_atomic_load((const u64*)(arow + ki * 32),
                                     __ATOMIC_RELAXED, __HIP_MEMORY_SCOPE_AGENT);
          h1[ki] = __hip_atomic_load((const u64*)(arow + ki * 32 + 4),
                                     __ATOMIC_RELAXED, __HIP_MEMORY_SCOPE_AGENT);
        }
        bad = 0;
#pragma unroll
        for (int ki = 0; ki < 16; ++ki) {
          bad |= (unsigned)((((h0[ki] >> 24) & 0xFFu) == 0x7Fu));
          bad |= (unsigned)((((h0[ki] >> 56) & 0xFFu) == 0x7Fu));
          bad |= (unsigned)((((h1[ki] >> 24) & 0xFFu) == 0x7Fu));
          bad |= (unsigned)((((h1[ki] >> 56) & 0xFFu) == 0x7Fu));
        }
        if (__any(bad)) __builtin_amdgcn_s_sleep(1); else break;
      } while (1);
      // ---- MFMA: A = h regs, B = Ws LDS
#pragma unroll
      for (int ki = 0; ki < 16; ++ki) {
        union { u64 v[2]; bf16x8 f; } ua;
        ua.v[0] = h0[ki]; ua.v[1] = h1[ki];
#pragma unroll
        for (int g = 0; g < 3; ++g)
#pragma unroll
          for (int nf = 0; nf < 2; ++nf) {
            bf16x8 b = *(const bf16x8*)&Ws[g * 32 + nf * 16 + lr][ki * 32 + lkq * 8];
            acc[g][nf] = __builtin_amdgcn_mfma_f32_16x16x32_bf16(ua.f, b, acc[g][nf], 0, 0, 0);
          }
      }
    }

    // ---- gates (xp regs, h state regs) + packed agent stores
    const size_t obase = (size_t)t * BATCH * EMB + off;
#pragma unroll
    for (int nf = 0; nf < 2; ++nf) {
      const int c = ct * 32 + nf * 16 + lr;
#pragma unroll
      for (int p = 0; p < 4; ++p) {
        const int m = wave * 16 + lkq * 4 + p;
        float xr = __bfloat162float(xc[0][nf][p]);
        float xz = __bfloat162float(xc[1][nf][p]);
        float xn = __bfloat162float(xc[2][nf][p]);
        float r = 1.f / (1.f + expf(-(xr + acc[0][nf][p] + bh[0][nf])));
        float z = 1.f / (1.f + expf(-(xz + acc[1][nf][p] + bh[1][nf])));
        float n = tanhf(xn + r * (acc[2][nf][p] + bh[2][nf]));
        float h = (1.f - z) * n + z * hp[nf][p];
        hp[nf][p] = h;
        bf16 hvb = __float2bfloat16(h);
        int mb = *(unsigned short*)&hvb;
        int pb = __shfl_xor(mb, 1);
        if (!(lr & 1)) {
          unsigned int pk = (unsigned int)mb | ((unsigned int)pb << 16);
          __hip_atomic_store((unsigned int*)(out + obase + (size_t)m * EMB + c), pk,
                             __ATOMIC_RELAXED, __HIP_MEMORY_SCOPE_AGENT);
        }
      }
    }

    // ---- wave-level drain (push stores toward visibility), xp prefetch
    asm volatile("s_waitcnt vmcnt(0)" ::: "memory");
    if (s + 1 < T_SEQ) {
      const int tn = dir ? (T_SEQ - 2 - s) : (s + 1);
      const size_t xb2 = (size_t)tn * BATCH * G3;
#pragma unroll
      for (int p = 0; p < 4; ++p) {
        const size_t xrow = xb2 + (size_t)(wave * 16 + lkq * 4 + p) * G3;
#pragma unroll
        for (int g = 0; g < 3; ++g)
#pragma unroll
          for (int nf = 0; nf < 2; ++nf)
            xc[g][nf][p] = xp[xrow + g * HID + ct * 32 + nf * 16 + lr];
      }
    }
  }
}

// ---------------------------------------------------------------------------
// K/V projections: ne batch-broadcast -> K/V collapse to [NT, EMB] fp32.
// ---------------------------------------------------------------------------
__global__ __launch_bounds__(256) void kv_kernel(
    const float* __restrict__ ne, const float* __restrict__ k_w,
    const float* __restrict__ k_b, const float* __restrict__ v_w,
    const float* __restrict__ v_b, float* __restrict__ kk,
    float* __restrict__ vv)
{
  const int e = blockIdx.x * 256 + threadIdx.x;
  if (e >= EMB) return;
#pragma unroll
  for (int s = 0; s < NTAG; ++s) {
    float a = k_b[e], c = v_b[e];
#pragma unroll
    for (int i = 0; i < NTAG; ++i) {
      float nv = ne[s * NTAG + i];
      a = fmaf(nv, k_w[e * NTAG + i], a);
      c = fmaf(nv, v_w[e * NTAG + i], c);
    }
    kk[s * EMB + e] = a;
    vv[s * EMB + e] = c;
  }
}

// ---------------------------------------------------------------------------
// Attention: 4 (tb,head) units per 256-thread block. S=14 keys, HD=128.
// ---------------------------------------------------------------------------
__global__ __launch_bounds__(256) void attn_kernel(
    const bf16* __restrict__ q, const float* __restrict__ kk,
    const float* __restrict__ vv, bf16* __restrict__ ao)
{
  const int unit = blockIdx.x * 4 + (threadIdx.x >> 6);
  const int h = unit & 7;
  const int tb = unit >> 3;
  const int lane = threadIdx.x & 63;
  const size_t qbase = (size_t)tb * EMB + h * 128;
  const int kbase = h * 128 + lane;
  float q0 = __bfloat162float(q[qbase + lane]);
  float q1 = __bfloat162float(q[qbase + 64 + lane]);
  float sc[NTAG];
#pragma unroll
  for (int j = 0; j < NTAG; ++j) {
    float p = q0 * kk[j * EMB + kbase] + q1 * kk[j * EMB + 64 + kbase];
#pragma unroll
    for (int d = 32; d; d >>= 1) p += __shfl_xor(p, d);
    sc[j] = p * 0.088388347648318447f;  // 1/sqrt(128)
  }
  float m = sc[0];
#pragma unroll
  for (int j = 1; j < NTAG; ++j) m = fmaxf(m, sc[j]);
  float sum = 0.f;
#pragma unroll
  for (int j = 0; j < NTAG; ++j) { sc[j] = expf(sc[j] - m); sum += sc[j]; }
  float inv = 1.f / sum;
  float o0 = 0.f, o1 = 0.f;
#pragma unroll
  for (int j = 0; j < NTAG; ++j) {
    float p = sc[j] * inv;
    o0 = fmaf(p, vv[j * EMB + kbase], o0);
    o1 = fmaf(p, vv[j * EMB + 64 + kbase], o1);
  }
  ao[qbase + lane] = __float2bfloat16(o0);
  ao[qbase + 64 + lane] = __float2bfloat16(o1);
}

// ---------------------------------------------------------------------------
// Fused final linear + ne-table logits: 4 (t,b) units per block.
// ---------------------------------------------------------------------------
__global__ __launch_bounds__(256) void dec_logits_kernel(
    const bf16* __restrict__ dec, const float* __restrict__ lin_w,
    const float* __restrict__ lin_b, const float* __restrict__ ne,
    float* __restrict__ logits)
{
  const int tb = blockIdx.x * 4 + (threadIdx.x >> 6);
  const int t = tb >> 6;
  const int b = tb & 63;
  const int lane = threadIdx.x & 63;
  const bf16* drow = dec + (size_t)tb * EMB;
  float dv[16];
#pragma unroll
  for (int i = 0; i < 16; ++i) dv[i] = __bfloat162float(drow[lane + 64 * i]);
  float dl[NTAG];
#pragma unroll
  for (int n = 0; n < NTAG; ++n) {
    float p = 0.f;
#pragma unroll
    for (int i = 0; i < 16; ++i)
      p = fmaf(dv[i], lin_w[n * EMB + lane + 64 * i], p);
#pragma unroll
    for (int d = 32; d; d >>= 1) p += __shfl_xor(p, d);
    dl[n] = p + lin_b[n];
  }
  if (lane < NTAG) {
    float acc = 0.f;
#pragma unroll
    for (int d2 = 0; d2 < NTAG; ++d2)
      acc = fmaf(dl[d2], ne[lane * NTAG + d2], acc);
    logits[((size_t)b * T_SEQ + t) * NTAG + lane] = acc * 0.26726124191242439f; // 1/sqrt(14)
  }
}

// ---------------------------------------------------------------------------
// CRF NLL per batch element (one wave per b; alpha recurrence over T).
// ---------------------------------------------------------------------------
__global__ __launch_bounds__(64) void crf_kernel(
    const float* __restrict__ logits, const int* __restrict__ labels,
    const float* __restrict__ cstart, const float* __restrict__ cend,
    const float* __restrict__ ctrans, float* __restrict__ lossb)
{
  const int b = blockIdx.x;
  const int lane = threadIdx.x;
  __shared__ float al[NTAG];
  __shared__ float tr[NTAG * NTAG];
  __shared__ float tmp[NTAG];
  const float* lg = logits + (size_t)b * T_SEQ * NTAG;
  const int* lab = labels + (size_t)b * T_SEQ;
  for (int i = lane; i < NTAG * NTAG; i += 64) tr[i] = ctrans[i];
  if (lane < NTAG) al[lane] = cstart[lane] + lg[lane];
  __syncthreads();
  for (int t = 1; t < T_SEQ; ++t) {
    float v = 0.f;
    if (lane < NTAG) {
      float mx = -1e30f;
#pragma unroll
      for (int i = 0; i < NTAG; ++i) mx = fmaxf(mx, al[i] + tr[i * NTAG + lane]);
      float sm = 0.f;
#pragma unroll
      for (int i = 0; i < NTAG; ++i) sm += expf(al[i] + tr[i * NTAG + lane] - mx);
      v = mx + logf(sm) + lg[t * NTAG + lane];
    }
    __syncthreads();
    if (lane < NTAG) al[lane] = v;
    __syncthreads();
  }
  float em = 0.f;
  for (int t = lane; t < T_SEQ; t += 64) em += lg[t * NTAG + lab[t]];
  float trs = 0.f;
  for (int t = lane; t < T_SEQ - 1; t += 64) trs += tr[lab[t] * NTAG + lab[t + 1]];
  float p = em + trs;
#pragma unroll
  for (int d = 32; d; d >>= 1) p += __shfl_xor(p, d);
  if (lane < NTAG) tmp[lane] = al[lane] + cend[lane];
  __syncthreads();
  if (lane == 0) {
    float num = p + cstart[lab[0]] + cend[lab[T_SEQ - 1]];
    float mx = tmp[0];
#pragma unroll
    for (int i = 1; i < NTAG; ++i) mx = fmaxf(mx, tmp[i]);
    float sm = 0.f;
#pragma unroll
    for (int i = 0; i < NTAG; ++i) sm += expf(tmp[i] - mx);
    float den = mx + logf(sm);
    lossb[b] = -(num - den);
  }
}

__global__ __launch_bounds__(64) void final_reduce(
    const float* __restrict__ lossb, float* __restrict__ out)
{
  float v = lossb[threadIdx.x];
#pragma unroll
  for (int d = 32; d; d >>= 1) v += __shfl_xor(v, d);
  if (threadIdx.x == 0) out[0] = v * (1.f / 64.f);
}

// ---------------------------------------------------------------------------
extern "C" void kernel_launch(void* const* d_in, const int* in_sizes, int n_in,
                              void* d_out, int out_size, void* d_ws, size_t ws_size,
                              hipStream_t stream)
{
  const float* features = (const float*)d_in[0];
  const int*   labels   = (const int*)d_in[1];
  const float* ne_table = (const float*)d_in[2];
  const float* g1_wih_f = (const float*)d_in[3];
  const float* g1_whh_f = (const float*)d_in[4];
  const float* g1_bih_f = (const float*)d_in[5];
  const float* g1_bhh_f = (const float*)d_in[6];
  const float* g1_wih_b = (const float*)d_in[7];
  const float* g1_whh_b = (const float*)d_in[8];
  const float* g1_bih_b = (const float*)d_in[9];
  const float* g1_bhh_b = (const float*)d_in[10];
  const float* g2_wih_f = (const float*)d_in[11];
  const float* g2_whh_f = (const float*)d_in[12];
  const float* g2_bih_f = (const float*)d_in[13];
  const float* g2_bhh_f = (const float*)d_in[14];
  const float* g2_wih_b = (const float*)d_in[15];
  const float* g2_whh_b = (const float*)d_in[16];
  const float* g2_bih_b = (const float*)d_in[17];
  const float* g2_bhh_b = (const float*)d_in[18];
  const float* q_w   = (const float*)d_in[19];
  const float* q_b   = (const float*)d_in[20];
  const float* k_w   = (const float*)d_in[21];
  const float* k_b   = (const float*)d_in[22];
  const float* v_w   = (const float*)d_in[23];
  const float* v_b   = (const float*)d_in[24];
  const float* out_w = (const float*)d_in[25];
  const float* out_b = (const float*)d_in[26];
  const float* lin_w = (const float*)d_in[27];
  const float* lin_b = (const float*)d_in[28];
  const float* crf_start = (const float*)d_in[29];
  const float* crf_end   = (const float*)d_in[30];
  const float* crf_trans = (const float*)d_in[31];

  // ---- workspace layout (~218 MB) ----
  const size_t NTB = (size_t)T_SEQ * BATCH;      // 16384
  char* base = (char*)d_ws;
  size_t off = 0;
  auto alloc = [&](size_t bytes) {
    char* p = base + off;
    off += (bytes + 255) & ~(size_t)255;
    return p;
  };
  bf16* xpA  = (bf16*)alloc(NTB * G3 * sizeof(bf16));   // xp fwd (gru1, then gru2)
  bf16* xpB  = (bf16*)alloc(NTB * G3 * sizeof(bf16));   // xp bwd
  bf16* enc  = (bf16*)alloc(NTB * EMB * sizeof(bf16));  // gru1 output
  bf16* bufD = (bf16*)alloc(NTB * EMB * sizeof(bf16));  // xT -> aoraw -> dec
  bf16* bufE = (bf16*)alloc(NTB * EMB * sizeof(bf16));  // q -> aofin
  float* kkbuf  = (float*)alloc((size_t)NTAG * EMB * sizeof(float));
  float* vvbuf  = (float*)alloc((size_t)NTAG * EMB * sizeof(float));
  float* logits = (float*)alloc(NTB * NTAG * sizeof(float));
  float* lossb  = (float*)alloc(64 * sizeof(float));
  // bf16 weight copies (~24.2 MB)
  bf16* w1if = (bf16*)alloc((size_t)G3 * FEATD * sizeof(bf16));
  bf16* w1ib = (bf16*)alloc((size_t)G3 * FEATD * sizeof(bf16));
  bf16* w1hf = (bf16*)alloc((size_t)G3 * HID * sizeof(bf16));
  bf16* w1hb = (bf16*)alloc((size_t)G3 * HID * sizeof(bf16));
  bf16* w2if = (bf16*)alloc((size_t)G3 * 2 * EMB * sizeof(bf16));
  bf16* w2ib = (bf16*)alloc((size_t)G3 * 2 * EMB * sizeof(bf16));
  bf16* w2hf = (bf16*)alloc((size_t)G3 * HID * sizeof(bf16));
  bf16* w2hb = (bf16*)alloc((size_t)G3 * HID * sizeof(bf16));
  bf16* wq   = (bf16*)alloc((size_t)EMB * EMB * sizeof(bf16));
  bf16* wo   = (bf16*)alloc((size_t)EMB * EMB * sizeof(bf16));
  (void)off; (void)ws_size; (void)in_sizes; (void)n_in; (void)out_size;

  bf16* xT = bufD;  // [T,B,FEAT] bf16, aliases bufD (dead before aoraw)

  const int M = (int)NTB;  // 16384
  dim3 blk(256);

  // 0. weight conversions fp32 -> bf16
  auto conv = [&](const float* s, bf16* d, size_t n) {
    f32_to_bf16<<<(int)((n / 4 + 255) / 256), blk, 0, stream>>>(s, d, (int)(n / 4));
  };
  conv(g1_wih_f, w1if, (size_t)G3 * FEATD);
  conv(g1_wih_b, w1ib, (size_t)G3 * FEATD);
  conv(g1_whh_f, w1hf, (size_t)G3 * HID);
  conv(g1_whh_b, w1hb, (size_t)G3 * HID);
  conv(g2_wih_f, w2if, (size_t)G3 * 2 * EMB);
  conv(g2_wih_b, w2ib, (size_t)G3 * 2 * EMB);
  conv(g2_whh_f, w2hf, (size_t)G3 * HID);
  conv(g2_whh_b, w2hb, (size_t)G3 * HID);
  conv(q_w, wq, (size_t)EMB * EMB);
  conv(out_w, wo, (size_t)EMB * EMB);

  // 0b. poison enc (data-as-flag sentinel; 0x7F byte -> bf16 top byte 0x7F)
  hipMemsetAsync(enc, 0x7F, NTB * EMB * sizeof(bf16), stream);

  // 1. features -> [T,B,FEAT] bf16
  transpose_feat<<<(BATCH * T_SEQ * FEATD + 255) / 256, blk, 0, stream>>>(features, xT);

  dim3 g_xp(G3 / 128, M / 128);   // (12,128)
  dim3 g_e(EMB / 128, M / 128);   // (8,128)

  // 2. GRU1 input projections
  gemm_mfma<<<g_xp, blk, 0, stream>>>(xT, FEATD, nullptr, 0, FEATD,
                                      w1if, FEATD, g1_bih_f, xpA, G3, M, G3, FEATD);
  gemm_mfma<<<g_xp, blk, 0, stream>>>(xT, FEATD, nullptr, 0, FEATD,
                                      w1ib, FEATD, g1_bih_b, xpB, G3, M, G3, FEATD);

  // 3. GRU1 recurrence -> enc (per-wave chains, data-as-flag)
  gru_persist<<<GRU_NBLK, blk, 0, stream>>>(xpA, xpB, w1hf, w1hb,
                                            g1_bhh_f, g1_bhh_b, enc);

  // 4. K/V (batch-independent) + Q projection -> bufE
  kv_kernel<<<4, blk, 0, stream>>>(ne_table, k_w, k_b, v_w, v_b, kkbuf, vvbuf);
  gemm_mfma<<<g_e, blk, 0, stream>>>(enc, EMB, nullptr, 0, EMB,
                                     wq, EMB, q_b, bufE, EMB, M, EMB, EMB);

  // 5. Attention (q=bufE -> aoraw=bufD) + output projection (-> aofin=bufE)
  attn_kernel<<<M * 2, blk, 0, stream>>>(bufE, kkbuf, vvbuf, bufD);
  gemm_mfma<<<g_e, blk, 0, stream>>>(bufD, EMB, nullptr, 0, EMB,
                                     wo, EMB, out_b, bufE, EMB, M, EMB, EMB);

  // 6. GRU2 input projections: dec_in = [enc, ao] via concat-A GEMM
  gemm_mfma<<<g_xp, blk, 0, stream>>>(enc, EMB, bufE, EMB, EMB,
                                      w2if, 2 * EMB, g2_bih_f, xpA, G3, M, G3, 2 * EMB);
  gemm_mfma<<<g_xp, blk, 0, stream>>>(enc, EMB, bufE, EMB, EMB,
                                      w2ib, 2 * EMB, g2_bih_b, xpB, G3, M, G3, 2 * EMB);

  // 6b. poison bufD (aoraw consumed by out-proj; now becomes dec target)
  hipMemsetAsync(bufD, 0x7F, NTB * EMB * sizeof(bf16), stream);

  // 7. GRU2 recurrence -> dec (bufD)
  gru_persist<<<GRU_NBLK, blk, 0, stream>>>(xpA, xpB, w2hf, w2hb,
                                            g2_bhh_f, g2_bhh_b, bufD);

  // 8. Final linear + ne logits
  dec_logits_kernel<<<M / 4, blk, 0, stream>>>(bufD, lin_w, lin_b, ne_table, logits);

  // 9. CRF NLL + mean
  crf_kernel<<<BATCH, 64, 0, stream>>>(logits, labels, crf_start, crf_end, crf_trans, lossb);
  final_reduce<<<1, 64, 0, stream>>>(lossb, (float*)d_out);
}

// Round 16
// 4300.800 us; speedup vs baseline: 1.2670x; 1.2670x over previous
//
#include <hip/hip_runtime.h>
#include <hip/hip_bf16.h>
#include <math.h>

typedef __hip_bfloat16 bf16;
typedef __bf16 bf16x8 __attribute__((ext_vector_type(8)));
typedef float  f32x4  __attribute__((ext_vector_type(4)));
typedef unsigned long long u64;

#define T_SEQ 256
#define BATCH 64
#define FEATD 188
#define HID   512
#define EMB   1024
#define NTAG  14
#define G3    1536   // 3*HID
#define GRU_NBLK 64  // 32 blocks/dir x 16 hidden cols
#define FLAG_LAYER (8 * T_SEQ * 32)   // ints/layer: (dir*4+wave) x step x 32 producers

// ---------------------------------------------------------------------------
// fp32 -> bf16 weight conversion (vectorized x4; all n % 4 == 0)
// ---------------------------------------------------------------------------
__global__ __launch_bounds__(256) void f32_to_bf16(
    const float* __restrict__ src, bf16* __restrict__ dst, int n4)
{
  int i = blockIdx.x * 256 + threadIdx.x;
  if (i >= n4) return;
  float4 v = *(const float4*)(src + (size_t)i * 4);
  bf16 o[4] = {__float2bfloat16(v.x), __float2bfloat16(v.y),
               __float2bfloat16(v.z), __float2bfloat16(v.w)};
  *(ushort4*)(dst + (size_t)i * 4) = *(ushort4*)o;
}

// ---------------------------------------------------------------------------
// MFMA GEMM: C[M,N] = concat(A1,A2)[M,K] @ W[N,K]^T + bias. (validated R3)
// ---------------------------------------------------------------------------
__global__ __launch_bounds__(256) void gemm_mfma(
    const bf16* __restrict__ A1, int lda1,
    const bf16* __restrict__ A2, int lda2, int K1,
    const bf16* __restrict__ W, int ldw,
    const float* __restrict__ bias,
    bf16* __restrict__ C, int ldc,
    int M, int N, int K)
{
  __shared__ __bf16 As[128][40];
  __shared__ __bf16 Bs[128][40];
  const int bm = blockIdx.y * 128;
  const int bn = blockIdx.x * 128;
  const int tid = threadIdx.x;
  const int wave = tid >> 6, lane = tid & 63;
  const int wr = wave >> 1, wc = wave & 1;
  const int lr = lane & 15, lk = (lane >> 4) << 3;
  f32x4 acc[4][4] = {};
  for (int k0 = 0; k0 < K; k0 += 32) {
#pragma unroll
    for (int p = 0; p < 4; ++p) {
      int i = tid + p * 256;
      int row = i >> 3, q = i & 7;
      int kg = k0 + q * 4;
      ushort4 va{0, 0, 0, 0}, vb{0, 0, 0, 0};
      if (kg < K) {
        const bf16* srca = (kg < K1) ? A1 + (size_t)(bm + row) * lda1 + kg
                                     : A2 + (size_t)(bm + row) * lda2 + (kg - K1);
        va = *(const ushort4*)srca;
        vb = *(const ushort4*)(W + (size_t)(bn + row) * ldw + kg);
      }
      *(ushort4*)&As[row][q * 4] = va;
      *(ushort4*)&Bs[row][q * 4] = vb;
    }
    __syncthreads();
    bf16x8 af[4], bf_[4];
#pragma unroll
    for (int i = 0; i < 4; ++i)
      af[i] = *(const bf16x8*)&As[wr * 64 + i * 16 + lr][lk];
#pragma unroll
    for (int j = 0; j < 4; ++j)
      bf_[j] = *(const bf16x8*)&Bs[wc * 64 + j * 16 + lr][lk];
#pragma unroll
    for (int i = 0; i < 4; ++i)
#pragma unroll
      for (int j = 0; j < 4; ++j)
        acc[i][j] = __builtin_amdgcn_mfma_f32_16x16x32_bf16(af[i], bf_[j], acc[i][j], 0, 0, 0);
    __syncthreads();
  }
#pragma unroll
  for (int j = 0; j < 4; ++j) {
    int n = bn + wc * 64 + j * 16 + lr;
    float bv = bias ? bias[n] : 0.f;
#pragma unroll
    for (int i = 0; i < 4; ++i) {
#pragma unroll
      for (int p = 0; p < 4; ++p) {
        int m = bm + wr * 64 + i * 16 + (lane >> 4) * 4 + p;
        C[(size_t)m * ldc + n] = __float2bfloat16(acc[i][j][p] + bv);
      }
    }
  }
}

// ---------------------------------------------------------------------------
// features [B,T,FEAT] fp32 -> xT [T,B,FEAT] bf16
// ---------------------------------------------------------------------------
__global__ __launch_bounds__(256) void transpose_feat(
    const float* __restrict__ f, bf16* __restrict__ xT)
{
  const int idx = blockIdx.x * 256 + threadIdx.x;
  const int total = BATCH * T_SEQ * FEATD;
  if (idx >= total) return;
  const int i = idx % FEATD;
  const int r = idx / FEATD;
  const int b = r / T_SEQ;
  const int t = r % T_SEQ;
  xT[((size_t)t * BATCH + b) * FEATD + i] = __float2bfloat16(f[idx]);
}

// ---------------------------------------------------------------------------
// Persistent bidirectional GRU layer, v12 = R14 per-wave chains, 64 blocks.
// 64 blocks (dir x 32 col-tiles of 16 cols), 256 threads = 4 waves.
// Rationale: R14's persist was largely HBM-fetch-bound on the xp stream at
// 32 CUs; 64 blocks double aggregate fetch BW. Per block: Ws = 48x512
// (49KB LDS), per-wave MFMA halves, xp/step halves. Protocol identical to
// R14: per-(dir,wave) chains, 32 producer flags/step, drain -> flag -> xp
// prefetch, zero __syncthreads in the loop.
// ---------------------------------------------------------------------------
__global__ __launch_bounds__(256, 1) void gru_persist(
    const bf16* __restrict__ xp_f, const bf16* __restrict__ xp_b,
    const bf16* __restrict__ whh_f, const bf16* __restrict__ whh_b,
    const float* __restrict__ bhh_f, const float* __restrict__ bhh_b,
    bf16* __restrict__ out, int* __restrict__ flags)
{
  const int blk = blockIdx.x;
  const int dir = blk >> 5;
  const int ct  = blk & 31;
  const bf16* xp   = dir ? xp_b  : xp_f;
  const bf16* whh  = dir ? whh_b : whh_f;
  const float* bhh = dir ? bhh_b : bhh_f;
  const int off = dir ? HID : 0;
  const int tid = threadIdx.x;
  const int wave = tid >> 6, lane = tid & 63;
  const int lr = lane & 15, lkq = lane >> 4;
  int* fl = flags + (size_t)(dir * 4 + wave) * (T_SEQ * 32);

  // weights: rows r = g*16 + n (n = local col 0..15), padded stride 520.
  // Read-only after init -> safe to share across drifting waves.
  __shared__ __bf16 Ws[48][520];
  for (int i = tid; i < 48 * 64; i += 256) {
    int r = i >> 6, q = i & 63;
    int grow = (r >> 4) * HID + ct * 16 + (r & 15);
    *(float4*)&Ws[r][q * 8] = *(const float4*)(whh + (size_t)grow * HID + q * 8);
  }
  __syncthreads();   // ONLY block-wide sync; before the loop.

  float bh[3];
#pragma unroll
  for (int g = 0; g < 3; ++g)
    bh[g] = bhh[g * HID + ct * 16 + lr];

  float hp[4] = {};   // own h state (rows wave*16+lkq*4+p, col ct*16+lr)

  // xp in registers, prologue for step 0
  bf16 xc[3][4];
  {
    const int t0 = dir ? (T_SEQ - 1) : 0;
    const size_t xb = (size_t)t0 * BATCH * G3;
#pragma unroll
    for (int p = 0; p < 4; ++p) {
      const size_t xrow = xb + (size_t)(wave * 16 + lkq * 4 + p) * G3;
#pragma unroll
      for (int g = 0; g < 3; ++g)
        xc[g][p] = xp[xrow + g * HID + ct * 16 + lr];
    }
  }

  for (int s = 0; s < T_SEQ; ++s) {
    const int t = dir ? (T_SEQ - 1 - s) : s;

    f32x4 acc[3] = {};
    if (s > 0) {
      // ---- poll THIS chain's 32 producer flags (wave-local, one 128B line)
      int ready = 0;
      do {
        int f = 1;
        if (lane < 32)
          f = __hip_atomic_load(&fl[(s - 1) * 32 + lane],
                                __ATOMIC_RELAXED, __HIP_MEMORY_SCOPE_AGENT);
        ready = __all(f != 0);
        if (!ready) __builtin_amdgcn_s_sleep(1);
      } while (!ready);
      __builtin_amdgcn_sched_barrier(0);
      // ---- batched coherent h loads (32 u64), then MFMA
      const int tp = dir ? t + 1 : t - 1;
      const bf16* arow = out + (size_t)tp * BATCH * EMB + off
                         + (size_t)(wave * 16 + lr) * EMB + lkq * 8;
      u64 h0[16], h1[16];
#pragma unroll
      for (int ki = 0; ki < 16; ++ki) {
        h0[ki] = __hip_atomic_load((const u64*)(arow + ki * 32),
                                   __ATOMIC_RELAXED, __HIP_MEMORY_SCOPE_AGENT);
        h1[ki] = __hip_atomic_load((const u64*)(arow + ki * 32 + 4),
                                   __ATOMIC_RELAXED, __HIP_MEMORY_SCOPE_AGENT);
      }
#pragma unroll
      for (int ki = 0; ki < 16; ++ki) {
        union { u64 v[2]; bf16x8 f; } ua;
        ua.v[0] = h0[ki]; ua.v[1] = h1[ki];
#pragma unroll
        for (int g = 0; g < 3; ++g) {
          bf16x8 b = *(const bf16x8*)&Ws[g * 16 + lr][ki * 32 + lkq * 8];
          acc[g] = __builtin_amdgcn_mfma_f32_16x16x32_bf16(ua.f, b, acc[g], 0, 0, 0);
        }
      }
    }

    // ---- gates (xp regs, h state regs) + packed agent stores
    const size_t obase = (size_t)t * BATCH * EMB + off;
    const int c = ct * 16 + lr;
#pragma unroll
    for (int p = 0; p < 4; ++p) {
      const int m = wave * 16 + lkq * 4 + p;
      float xr = __bfloat162float(xc[0][p]);
      float xz = __bfloat162float(xc[1][p]);
      float xn = __bfloat162float(xc[2][p]);
      float r = 1.f / (1.f + expf(-(xr + acc[0][p] + bh[0])));
      float z = 1.f / (1.f + expf(-(xz + acc[1][p] + bh[1])));
      float n = tanhf(xn + r * (acc[2][p] + bh[2]));
      float h = (1.f - z) * n + z * hp[p];
      hp[p] = h;
      bf16 hvb = __float2bfloat16(h);
      int mb = *(unsigned short*)&hvb;
      int pb = __shfl_xor(mb, 1);
      if (!(lr & 1)) {
        unsigned int pk = (unsigned int)mb | ((unsigned int)pb << 16);
        __hip_atomic_store((unsigned int*)(out + obase + (size_t)m * EMB + c), pk,
                           __ATOMIC_RELAXED, __HIP_MEMORY_SCOPE_AGENT);
      }
    }

    // ---- wave-level protocol: drain own stores -> flag -> xp prefetch
    asm volatile("s_waitcnt vmcnt(0)" ::: "memory");
    if (s + 1 < T_SEQ) {
      if (lane == 0)
        __hip_atomic_store(&fl[s * 32 + ct], 1,
                           __ATOMIC_RELAXED, __HIP_MEMORY_SCOPE_AGENT);
      // prefetch next step's xp (latency hides under next poll)
      const int tn = dir ? (T_SEQ - 2 - s) : (s + 1);
      const size_t xb2 = (size_t)tn * BATCH * G3;
#pragma unroll
      for (int p = 0; p < 4; ++p) {
        const size_t xrow = xb2 + (size_t)(wave * 16 + lkq * 4 + p) * G3;
#pragma unroll
        for (int g = 0; g < 3; ++g)
          xc[g][p] = xp[xrow + g * HID + ct * 16 + lr];
      }
    }
  }
}

// ---------------------------------------------------------------------------
// K/V projections: ne batch-broadcast -> K/V collapse to [NT, EMB] fp32.
// ---------------------------------------------------------------------------
__global__ __launch_bounds__(256) void kv_kernel(
    const float* __restrict__ ne, const float* __restrict__ k_w,
    const float* __restrict__ k_b, const float* __restrict__ v_w,
    const float* __restrict__ v_b, float* __restrict__ kk,
    float* __restrict__ vv)
{
  const int e = blockIdx.x * 256 + threadIdx.x;
  if (e >= EMB) return;
#pragma unroll
  for (int s = 0; s < NTAG; ++s) {
    float a = k_b[e], c = v_b[e];
#pragma unroll
    for (int i = 0; i < NTAG; ++i) {
      float nv = ne[s * NTAG + i];
      a = fmaf(nv, k_w[e * NTAG + i], a);
      c = fmaf(nv, v_w[e * NTAG + i], c);
    }
    kk[s * EMB + e] = a;
    vv[s * EMB + e] = c;
  }
}

// ---------------------------------------------------------------------------
// Attention: 4 (tb,head) units per 256-thread block. S=14 keys, HD=128.
// ---------------------------------------------------------------------------
__global__ __launch_bounds__(256) void attn_kernel(
    const bf16* __restrict__ q, const float* __restrict__ kk,
    const float* __restrict__ vv, bf16* __restrict__ ao)
{
  const int unit = blockIdx.x * 4 + (threadIdx.x >> 6);
  const int h = unit & 7;
  const int tb = unit >> 3;
  const int lane = threadIdx.x & 63;
  const size_t qbase = (size_t)tb * EMB + h * 128;
  const int kbase = h * 128 + lane;
  float q0 = __bfloat162float(q[qbase + lane]);
  float q1 = __bfloat162float(q[qbase + 64 + lane]);
  float sc[NTAG];
#pragma unroll
  for (int j = 0; j < NTAG; ++j) {
    float p = q0 * kk[j * EMB + kbase] + q1 * kk[j * EMB + 64 + kbase];
#pragma unroll
    for (int d = 32; d; d >>= 1) p += __shfl_xor(p, d);
    sc[j] = p * 0.088388347648318447f;  // 1/sqrt(128)
  }
  float m = sc[0];
#pragma unroll
  for (int j = 1; j < NTAG; ++j) m = fmaxf(m, sc[j]);
  float sum = 0.f;
#pragma unroll
  for (int j = 0; j < NTAG; ++j) { sc[j] = expf(sc[j] - m); sum += sc[j]; }
  float inv = 1.f / sum;
  float o0 = 0.f, o1 = 0.f;
#pragma unroll
  for (int j = 0; j < NTAG; ++j) {
    float p = sc[j] * inv;
    o0 = fmaf(p, vv[j * EMB + kbase], o0);
    o1 = fmaf(p, vv[j * EMB + 64 + kbase], o1);
  }
  ao[qbase + lane] = __float2bfloat16(o0);
  ao[qbase + 64 + lane] = __float2bfloat16(o1);
}

// ---------------------------------------------------------------------------
// Fused final linear + ne-table logits: 4 (t,b) units per block.
// ---------------------------------------------------------------------------
__global__ __launch_bounds__(256) void dec_logits_kernel(
    const bf16* __restrict__ dec, const float* __restrict__ lin_w,
    const float* __restrict__ lin_b, const float* __restrict__ ne,
    float* __restrict__ logits)
{
  const int tb = blockIdx.x * 4 + (threadIdx.x >> 6);
  const int t = tb >> 6;
  const int b = tb & 63;
  const int lane = threadIdx.x & 63;
  const bf16* drow = dec + (size_t)tb * EMB;
  float dv[16];
#pragma unroll
  for (int i = 0; i < 16; ++i) dv[i] = __bfloat162float(drow[lane + 64 * i]);
  float dl[NTAG];
#pragma unroll
  for (int n = 0; n < NTAG; ++n) {
    float p = 0.f;
#pragma unroll
    for (int i = 0; i < 16; ++i)
      p = fmaf(dv[i], lin_w[n * EMB + lane + 64 * i], p);
#pragma unroll
    for (int d = 32; d; d >>= 1) p += __shfl_xor(p, d);
    dl[n] = p + lin_b[n];
  }
  if (lane < NTAG) {
    float acc = 0.f;
#pragma unroll
    for (int d2 = 0; d2 < NTAG; ++d2)
      acc = fmaf(dl[d2], ne[lane * NTAG + d2], acc);
    logits[((size_t)b * T_SEQ + t) * NTAG + lane] = acc * 0.26726124191242439f; // 1/sqrt(14)
  }
}

// ---------------------------------------------------------------------------
// CRF NLL per batch element (one wave per b; alpha recurrence over T).
// ---------------------------------------------------------------------------
__global__ __launch_bounds__(64) void crf_kernel(
    const float* __restrict__ logits, const int* __restrict__ labels,
    const float* __restrict__ cstart, const float* __restrict__ cend,
    const float* __restrict__ ctrans, float* __restrict__ lossb)
{
  const int b = blockIdx.x;
  const int lane = threadIdx.x;
  __shared__ float al[NTAG];
  __shared__ float tr[NTAG * NTAG];
  __shared__ float tmp[NTAG];
  const float* lg = logits + (size_t)b * T_SEQ * NTAG;
  const int* lab = labels + (size_t)b * T_SEQ;
  for (int i = lane; i < NTAG * NTAG; i += 64) tr[i] = ctrans[i];
  if (lane < NTAG) al[lane] = cstart[lane] + lg[lane];
  __syncthreads();
  for (int t = 1; t < T_SEQ; ++t) {
    float v = 0.f;
    if (lane < NTAG) {
      float mx = -1e30f;
#pragma unroll
      for (int i = 0; i < NTAG; ++i) mx = fmaxf(mx, al[i] + tr[i * NTAG + lane]);
      float sm = 0.f;
#pragma unroll
      for (int i = 0; i < NTAG; ++i) sm += expf(al[i] + tr[i * NTAG + lane] - mx);
      v = mx + logf(sm) + lg[t * NTAG + lane];
    }
    __syncthreads();
    if (lane < NTAG) al[lane] = v;
    __syncthreads();
  }
  float em = 0.f;
  for (int t = lane; t < T_SEQ; t += 64) em += lg[t * NTAG + lab[t]];
  float trs = 0.f;
  for (int t = lane; t < T_SEQ - 1; t += 64) trs += tr[lab[t] * NTAG + lab[t + 1]];
  float p = em + trs;
#pragma unroll
  for (int d = 32; d; d >>= 1) p += __shfl_xor(p, d);
  if (lane < NTAG) tmp[lane] = al[lane] + cend[lane];
  __syncthreads();
  if (lane == 0) {
    float num = p + cstart[lab[0]] + cend[lab[T_SEQ - 1]];
    float mx = tmp[0];
#pragma unroll
    for (int i = 1; i < NTAG; ++i) mx = fmaxf(mx, tmp[i]);
    float sm = 0.f;
#pragma unroll
    for (int i = 0; i < NTAG; ++i) sm += expf(tmp[i] - mx);
    float den = mx + logf(sm);
    lossb[b] = -(num - den);
  }
}

__global__ __launch_bounds__(64) void final_reduce(
    const float* __restrict__ lossb, float* __restrict__ out)
{
  float v = lossb[threadIdx.x];
#pragma unroll
  for (int d = 32; d; d >>= 1) v += __shfl_xor(v, d);
  if (threadIdx.x == 0) out[0] = v * (1.f / 64.f);
}

// ---------------------------------------------------------------------------
extern "C" void kernel_launch(void* const* d_in, const int* in_sizes, int n_in,
                              void* d_out, int out_size, void* d_ws, size_t ws_size,
                              hipStream_t stream)
{
  const float* features = (const float*)d_in[0];
  const int*   labels   = (const int*)d_in[1];
  const float* ne_table = (const float*)d_in[2];
  const float* g1_wih_f = (const float*)d_in[3];
  const float* g1_whh_f = (const float*)d_in[4];
  const float* g1_bih_f = (const float*)d_in[5];
  const float* g1_bhh_f = (const float*)d_in[6];
  const float* g1_wih_b = (const float*)d_in[7];
  const float* g1_whh_b = (const float*)d_in[8];
  const float* g1_bih_b = (const float*)d_in[9];
  const float* g1_bhh_b = (const float*)d_in[10];
  const float* g2_wih_f = (const float*)d_in[11];
  const float* g2_whh_f = (const float*)d_in[12];
  const float* g2_bih_f = (const float*)d_in[13];
  const float* g2_bhh_f = (const float*)d_in[14];
  const float* g2_wih_b = (const float*)d_in[15];
  const float* g2_whh_b = (const float*)d_in[16];
  const float* g2_bih_b = (const float*)d_in[17];
  const float* g2_bhh_b = (const float*)d_in[18];
  const float* q_w   = (const float*)d_in[19];
  const float* q_b   = (const float*)d_in[20];
  const float* k_w   = (const float*)d_in[21];
  const float* k_b   = (const float*)d_in[22];
  const float* v_w   = (const float*)d_in[23];
  const float* v_b   = (const float*)d_in[24];
  const float* out_w = (const float*)d_in[25];
  const float* out_b = (const float*)d_in[26];
  const float* lin_w = (const float*)d_in[27];
  const float* lin_b = (const float*)d_in[28];
  const float* crf_start = (const float*)d_in[29];
  const float* crf_end   = (const float*)d_in[30];
  const float* crf_trans = (const float*)d_in[31];

  // ---- workspace layout (~219 MB) ----
  const size_t NTB = (size_t)T_SEQ * BATCH;      // 16384
  char* base = (char*)d_ws;
  size_t off = 0;
  auto alloc = [&](size_t bytes) {
    char* p = base + off;
    off += (bytes + 255) & ~(size_t)255;
    return p;
  };
  bf16* xpA  = (bf16*)alloc(NTB * G3 * sizeof(bf16));   // xp fwd (gru1, then gru2)
  bf16* xpB  = (bf16*)alloc(NTB * G3 * sizeof(bf16));   // xp bwd
  bf16* enc  = (bf16*)alloc(NTB * EMB * sizeof(bf16));  // gru1 output
  bf16* bufD = (bf16*)alloc(NTB * EMB * sizeof(bf16));  // xT -> aoraw -> dec
  bf16* bufE = (bf16*)alloc(NTB * EMB * sizeof(bf16));  // q -> aofin
  float* kkbuf  = (float*)alloc((size_t)NTAG * EMB * sizeof(float));
  float* vvbuf  = (float*)alloc((size_t)NTAG * EMB * sizeof(float));
  float* logits = (float*)alloc(NTB * NTAG * sizeof(float));
  float* lossb  = (float*)alloc(64 * sizeof(float));
  int*   flags  = (int*)alloc(2 * FLAG_LAYER * sizeof(int)); // layer1, layer2
  // bf16 weight copies (~24.2 MB)
  bf16* w1if = (bf16*)alloc((size_t)G3 * FEATD * sizeof(bf16));
  bf16* w1ib = (bf16*)alloc((size_t)G3 * FEATD * sizeof(bf16));
  bf16* w1hf = (bf16*)alloc((size_t)G3 * HID * sizeof(bf16));
  bf16* w1hb = (bf16*)alloc((size_t)G3 * HID * sizeof(bf16));
  bf16* w2if = (bf16*)alloc((size_t)G3 * 2 * EMB * sizeof(bf16));
  bf16* w2ib = (bf16*)alloc((size_t)G3 * 2 * EMB * sizeof(bf16));
  bf16* w2hf = (bf16*)alloc((size_t)G3 * HID * sizeof(bf16));
  bf16* w2hb = (bf16*)alloc((size_t)G3 * HID * sizeof(bf16));
  bf16* wq   = (bf16*)alloc((size_t)EMB * EMB * sizeof(bf16));
  bf16* wo   = (bf16*)alloc((size_t)EMB * EMB * sizeof(bf16));
  (void)off; (void)ws_size; (void)in_sizes; (void)n_in; (void)out_size;

  bf16* xT = bufD;  // [T,B,FEAT] bf16, aliases bufD (dead before aoraw)

  const int M = (int)NTB;  // 16384
  dim3 blk(256);

  // 0. zero flag regions (each launch -> replay-deterministic)
  hipMemsetAsync(flags, 0, 2 * FLAG_LAYER * sizeof(int), stream);

  // 0b. weight conversions fp32 -> bf16
  auto conv = [&](const float* s, bf16* d, size_t n) {
    f32_to_bf16<<<(int)((n / 4 + 255) / 256), blk, 0, stream>>>(s, d, (int)(n / 4));
  };
  conv(g1_wih_f, w1if, (size_t)G3 * FEATD);
  conv(g1_wih_b, w1ib, (size_t)G3 * FEATD);
  conv(g1_whh_f, w1hf, (size_t)G3 * HID);
  conv(g1_whh_b, w1hb, (size_t)G3 * HID);
  conv(g2_wih_f, w2if, (size_t)G3 * 2 * EMB);
  conv(g2_wih_b, w2ib, (size_t)G3 * 2 * EMB);
  conv(g2_whh_f, w2hf, (size_t)G3 * HID);
  conv(g2_whh_b, w2hb, (size_t)G3 * HID);
  conv(q_w, wq, (size_t)EMB * EMB);
  conv(out_w, wo, (size_t)EMB * EMB);

  // 1. features -> [T,B,FEAT] bf16
  transpose_feat<<<(BATCH * T_SEQ * FEATD + 255) / 256, blk, 0, stream>>>(features, xT);

  dim3 g_xp(G3 / 128, M / 128);   // (12,128)
  dim3 g_e(EMB / 128, M / 128);   // (8,128)

  // 2. GRU1 input projections
  gemm_mfma<<<g_xp, blk, 0, stream>>>(xT, FEATD, nullptr, 0, FEATD,
                                      w1if, FEATD, g1_bih_f, xpA, G3, M, G3, FEATD);
  gemm_mfma<<<g_xp, blk, 0, stream>>>(xT, FEATD, nullptr, 0, FEATD,
                                      w1ib, FEATD, g1_bih_b, xpB, G3, M, G3, FEATD);

  // 3. GRU1 recurrence -> enc (per-wave chains, 64 blocks)
  gru_persist<<<GRU_NBLK, blk, 0, stream>>>(xpA, xpB, w1hf, w1hb,
                                            g1_bhh_f, g1_bhh_b, enc, flags);

  // 4. K/V (batch-independent) + Q projection -> bufE
  kv_kernel<<<4, blk, 0, stream>>>(ne_table, k_w, k_b, v_w, v_b, kkbuf, vvbuf);
  gemm_mfma<<<g_e, blk, 0, stream>>>(enc, EMB, nullptr, 0, EMB,
                                     wq, EMB, q_b, bufE, EMB, M, EMB, EMB);

  // 5. Attention (q=bufE -> aoraw=bufD) + output projection (-> aofin=bufE)
  attn_kernel<<<M * 2, blk, 0, stream>>>(bufE, kkbuf, vvbuf, bufD);
  gemm_mfma<<<g_e, blk, 0, stream>>>(bufD, EMB, nullptr, 0, EMB,
                                     wo, EMB, out_b, bufE, EMB, M, EMB, EMB);

  // 6. GRU2 input projections: dec_in = [enc, ao] via concat-A GEMM
  gemm_mfma<<<g_xp, blk, 0, stream>>>(enc, EMB, bufE, EMB, EMB,
                                      w2if, 2 * EMB, g2_bih_f, xpA, G3, M, G3, 2 * EMB);
  gemm_mfma<<<g_xp, blk, 0, stream>>>(enc, EMB, bufE, EMB, EMB,
                                      w2ib, 2 * EMB, g2_bih_b, xpB, G3, M, G3, 2 * EMB);

  // 7. GRU2 recurrence -> dec (bufD; aoraw dead)
  gru_persist<<<GRU_NBLK, blk, 0, stream>>>(xpA, xpB, w2hf, w2hb,
                                            g2_bhh_f, g2_bhh_b, bufD,
                                            flags + FLAG_LAYER);

  // 8. Final linear + ne logits
  dec_logits_kernel<<<M / 4, blk, 0, stream>>>(bufD, lin_w, lin_b, ne_table, logits);

  // 9. CRF NLL + mean
  crf_kernel<<<BATCH, 64, 0, stream>>>(logits, labels, crf_start, crf_end, crf_trans, lossb);
  final_reduce<<<1, 64, 0, stream>>>(lossb, (float*)d_out);
}

// Round 17
// 4151.270 us; speedup vs baseline: 1.3126x; 1.0360x over previous
//
#include <hip/hip_runtime.h>
#include <hip/hip_bf16.h>
#include <math.h>

typedef __hip_bfloat16 bf16;
typedef __bf16 bf16x8 __attribute__((ext_vector_type(8)));
typedef float  f32x4  __attribute__((ext_vector_type(4)));
typedef unsigned long long u64;
typedef unsigned int u32;

#define T_SEQ 256
#define BATCH 64
#define FEATD 188
#define FPAD  192    // FEATD zero-padded to 16B-friendly multiple of 32
#define HID   512
#define EMB   1024
#define NTAG  14
#define G3    1536   // 3*HID
#define GRU_NBLK 64  // 32 blocks/dir x 16 hidden cols
#define FLAG_LAYER (8 * T_SEQ * 32)   // ints/layer: (dir*4+wave) x step x 32 producers

// ---------------------------------------------------------------------------
// fp32 -> bf16 weight conversion (vectorized x4; all n % 4 == 0)
// ---------------------------------------------------------------------------
__global__ __launch_bounds__(256) void f32_to_bf16(
    const float* __restrict__ src, bf16* __restrict__ dst, int n4)
{
  int i = blockIdx.x * 256 + threadIdx.x;
  if (i >= n4) return;
  float4 v = *(const float4*)(src + (size_t)i * 4);
  bf16 o[4] = {__float2bfloat16(v.x), __float2bfloat16(v.y),
               __float2bfloat16(v.z), __float2bfloat16(v.w)};
  *(ushort4*)(dst + (size_t)i * 4) = *(ushort4*)o;
}

// fp32 [rows x 188] -> bf16 [rows x 192] zero-padded
__global__ __launch_bounds__(256) void f32_to_bf16_pad(
    const float* __restrict__ src, bf16* __restrict__ dst, int rows)
{
  int idx = blockIdx.x * 256 + threadIdx.x;
  int total = rows * FPAD;
  if (idx >= total) return;
  int r = idx / FPAD, i = idx - r * FPAD;
  float v = (i < FEATD) ? src[(size_t)r * FEATD + i] : 0.f;
  dst[idx] = __float2bfloat16(v);
}

// ---------------------------------------------------------------------------
// MFMA GEMM v13: C[M,N] = concat(A1,A2)[M,K] @ W[N,K]^T + bias.
// m97-style staging: linear LDS [128][32] + global_load_lds width=16
// (wave-uniform LDS base + lane*16B; per-lane global src). All K multiples
// of 32; all row strides multiples of 16B (FEATD padded to 192).
// 128x128 tile, 4 waves 2x2, 64x64/wave, K-step 32.
// ---------------------------------------------------------------------------
__global__ __launch_bounds__(256) void gemm_mfma(
    const bf16* __restrict__ A1, int lda1,
    const bf16* __restrict__ A2, int lda2, int K1,
    const bf16* __restrict__ W, int ldw,
    const float* __restrict__ bias,
    bf16* __restrict__ C, int ldc,
    int M, int N, int K)
{
  __shared__ __align__(16) __bf16 As[128 * 32];
  __shared__ __align__(16) __bf16 Bs[128 * 32];
  const int bm = blockIdx.y * 128;
  const int bn = blockIdx.x * 128;
  const int tid = threadIdx.x;
  const int wave = tid >> 6, lane = tid & 63;
  const int wr = wave >> 1, wc = wave & 1;
  const int lr = lane & 15, lk = (lane >> 4) << 3;
  // staging map: issue j: row_local = wave*16 + j*64 + lane/4, kcol = (lane&3)*8
  const int srow = wave * 16 + (lane >> 2);
  const int scol = (lane & 3) * 8;
  f32x4 acc[4][4] = {};
  for (int k0 = 0; k0 < K; k0 += 32) {
#pragma unroll
    for (int j = 0; j < 2; ++j) {
      const int row = srow + j * 64;
      const int kg = k0 + scol;
      const bf16* srca = (kg < K1) ? A1 + (size_t)(bm + row) * lda1 + kg
                                   : A2 + (size_t)(bm + row) * lda2 + (kg - K1);
      const bf16* srcb = W + (size_t)(bn + row) * ldw + kg;
      __builtin_amdgcn_global_load_lds(
          (const __attribute__((address_space(1))) u32*)srca,
          (__attribute__((address_space(3))) u32*)(&As[j * 2048 + wave * 512]),
          16, 0, 0);
      __builtin_amdgcn_global_load_lds(
          (const __attribute__((address_space(1))) u32*)srcb,
          (__attribute__((address_space(3))) u32*)(&Bs[j * 2048 + wave * 512]),
          16, 0, 0);
    }
    __syncthreads();   // drains vmcnt (incl. global_load_lds) before barrier
    bf16x8 af[4], bf_[4];
#pragma unroll
    for (int i = 0; i < 4; ++i)
      af[i] = *(const bf16x8*)&As[(wr * 64 + i * 16 + lr) * 32 + lk];
#pragma unroll
    for (int j = 0; j < 4; ++j)
      bf_[j] = *(const bf16x8*)&Bs[(wc * 64 + j * 16 + lr) * 32 + lk];
#pragma unroll
    for (int i = 0; i < 4; ++i)
#pragma unroll
      for (int j = 0; j < 4; ++j)
        acc[i][j] = __builtin_amdgcn_mfma_f32_16x16x32_bf16(af[i], bf_[j], acc[i][j], 0, 0, 0);
    __syncthreads();
  }
#pragma unroll
  for (int j = 0; j < 4; ++j) {
    int n = bn + wc * 64 + j * 16 + lr;
    float bv = bias ? bias[n] : 0.f;
#pragma unroll
    for (int i = 0; i < 4; ++i) {
#pragma unroll
      for (int p = 0; p < 4; ++p) {
        int m = bm + wr * 64 + i * 16 + (lane >> 4) * 4 + p;
        C[(size_t)m * ldc + n] = __float2bfloat16(acc[i][j][p] + bv);
      }
    }
  }
}

// ---------------------------------------------------------------------------
// features [B,T,FEAT] fp32 -> xT [T,B,FPAD] bf16 (zero-padded)
// ---------------------------------------------------------------------------
__global__ __launch_bounds__(256) void transpose_feat(
    const float* __restrict__ f, bf16* __restrict__ xT)
{
  const int idx = blockIdx.x * 256 + threadIdx.x;
  const int total = BATCH * T_SEQ * FPAD;
  if (idx >= total) return;
  const int i = idx % FPAD;
  const int r = idx / FPAD;
  const int t = r / BATCH;
  const int b = r % BATCH;
  float v = (i < FEATD) ? f[((size_t)b * T_SEQ + t) * FEATD + i] : 0.f;
  xT[idx] = __float2bfloat16(v);
}

// ---------------------------------------------------------------------------
// Persistent bidirectional GRU layer, v12 (R16 verbatim; best 1695us).
// 64 blocks (dir x 32 col-tiles of 16 cols), 256 threads = 4 waves.
// Per-(dir,wave) chains, 32 producer flags/step, drain -> flag -> xp
// prefetch, zero __syncthreads in the loop.
// ---------------------------------------------------------------------------
__global__ __launch_bounds__(256, 1) void gru_persist(
    const bf16* __restrict__ xp_f, const bf16* __restrict__ xp_b,
    const bf16* __restrict__ whh_f, const bf16* __restrict__ whh_b,
    const float* __restrict__ bhh_f, const float* __restrict__ bhh_b,
    bf16* __restrict__ out, int* __restrict__ flags)
{
  const int blk = blockIdx.x;
  const int dir = blk >> 5;
  const int ct  = blk & 31;
  const bf16* xp   = dir ? xp_b  : xp_f;
  const bf16* whh  = dir ? whh_b : whh_f;
  const float* bhh = dir ? bhh_b : bhh_f;
  const int off = dir ? HID : 0;
  const int tid = threadIdx.x;
  const int wave = tid >> 6, lane = tid & 63;
  const int lr = lane & 15, lkq = lane >> 4;
  int* fl = flags + (size_t)(dir * 4 + wave) * (T_SEQ * 32);

  __shared__ __bf16 Ws[48][520];
  for (int i = tid; i < 48 * 64; i += 256) {
    int r = i >> 6, q = i & 63;
    int grow = (r >> 4) * HID + ct * 16 + (r & 15);
    *(float4*)&Ws[r][q * 8] = *(const float4*)(whh + (size_t)grow * HID + q * 8);
  }
  __syncthreads();   // ONLY block-wide sync; before the loop.

  float bh[3];
#pragma unroll
  for (int g = 0; g < 3; ++g)
    bh[g] = bhh[g * HID + ct * 16 + lr];

  float hp[4] = {};

  bf16 xc[3][4];
  {
    const int t0 = dir ? (T_SEQ - 1) : 0;
    const size_t xb = (size_t)t0 * BATCH * G3;
#pragma unroll
    for (int p = 0; p < 4; ++p) {
      const size_t xrow = xb + (size_t)(wave * 16 + lkq * 4 + p) * G3;
#pragma unroll
      for (int g = 0; g < 3; ++g)
        xc[g][p] = xp[xrow + g * HID + ct * 16 + lr];
    }
  }

  for (int s = 0; s < T_SEQ; ++s) {
    const int t = dir ? (T_SEQ - 1 - s) : s;

    f32x4 acc[3] = {};
    if (s > 0) {
      int ready = 0;
      do {
        int f = 1;
        if (lane < 32)
          f = __hip_atomic_load(&fl[(s - 1) * 32 + lane],
                                __ATOMIC_RELAXED, __HIP_MEMORY_SCOPE_AGENT);
        ready = __all(f != 0);
        if (!ready) __builtin_amdgcn_s_sleep(1);
      } while (!ready);
      __builtin_amdgcn_sched_barrier(0);
      const int tp = dir ? t + 1 : t - 1;
      const bf16* arow = out + (size_t)tp * BATCH * EMB + off
                         + (size_t)(wave * 16 + lr) * EMB + lkq * 8;
      u64 h0[16], h1[16];
#pragma unroll
      for (int ki = 0; ki < 16; ++ki) {
        h0[ki] = __hip_atomic_load((const u64*)(arow + ki * 32),
                                   __ATOMIC_RELAXED, __HIP_MEMORY_SCOPE_AGENT);
        h1[ki] = __hip_atomic_load((const u64*)(arow + ki * 32 + 4),
                                   __ATOMIC_RELAXED, __HIP_MEMORY_SCOPE_AGENT);
      }
#pragma unroll
      for (int ki = 0; ki < 16; ++ki) {
        union { u64 v[2]; bf16x8 f; } ua;
        ua.v[0] = h0[ki]; ua.v[1] = h1[ki];
#pragma unroll
        for (int g = 0; g < 3; ++g) {
          bf16x8 b = *(const bf16x8*)&Ws[g * 16 + lr][ki * 32 + lkq * 8];
          acc[g] = __builtin_amdgcn_mfma_f32_16x16x32_bf16(ua.f, b, acc[g], 0, 0, 0);
        }
      }
    }

    const size_t obase = (size_t)t * BATCH * EMB + off;
    const int c = ct * 16 + lr;
#pragma unroll
    for (int p = 0; p < 4; ++p) {
      const int m = wave * 16 + lkq * 4 + p;
      float xr = __bfloat162float(xc[0][p]);
      float xz = __bfloat162float(xc[1][p]);
      float xn = __bfloat162float(xc[2][p]);
      float r = 1.f / (1.f + expf(-(xr + acc[0][p] + bh[0])));
      float z = 1.f / (1.f + expf(-(xz + acc[1][p] + bh[1])));
      float n = tanhf(xn + r * (acc[2][p] + bh[2]));
      float h = (1.f - z) * n + z * hp[p];
      hp[p] = h;
      bf16 hvb = __float2bfloat16(h);
      int mb = *(unsigned short*)&hvb;
      int pb = __shfl_xor(mb, 1);
      if (!(lr & 1)) {
        unsigned int pk = (unsigned int)mb | ((unsigned int)pb << 16);
        __hip_atomic_store((unsigned int*)(out + obase + (size_t)m * EMB + c), pk,
                           __ATOMIC_RELAXED, __HIP_MEMORY_SCOPE_AGENT);
      }
    }

    asm volatile("s_waitcnt vmcnt(0)" ::: "memory");
    if (s + 1 < T_SEQ) {
      if (lane == 0)
        __hip_atomic_store(&fl[s * 32 + ct], 1,
                           __ATOMIC_RELAXED, __HIP_MEMORY_SCOPE_AGENT);
      const int tn = dir ? (T_SEQ - 2 - s) : (s + 1);
      const size_t xb2 = (size_t)tn * BATCH * G3;
#pragma unroll
      for (int p = 0; p < 4; ++p) {
        const size_t xrow = xb2 + (size_t)(wave * 16 + lkq * 4 + p) * G3;
#pragma unroll
        for (int g = 0; g < 3; ++g)
          xc[g][p] = xp[xrow + g * HID + ct * 16 + lr];
      }
    }
  }
}

// ---------------------------------------------------------------------------
// K/V projections: ne batch-broadcast -> K/V collapse to [NT, EMB] fp32.
// ---------------------------------------------------------------------------
__global__ __launch_bounds__(256) void kv_kernel(
    const float* __restrict__ ne, const float* __restrict__ k_w,
    const float* __restrict__ k_b, const float* __restrict__ v_w,
    const float* __restrict__ v_b, float* __restrict__ kk,
    float* __restrict__ vv)
{
  const int e = blockIdx.x * 256 + threadIdx.x;
  if (e >= EMB) return;
#pragma unroll
  for (int s = 0; s < NTAG; ++s) {
    float a = k_b[e], c = v_b[e];
#pragma unroll
    for (int i = 0; i < NTAG; ++i) {
      float nv = ne[s * NTAG + i];
      a = fmaf(nv, k_w[e * NTAG + i], a);
      c = fmaf(nv, v_w[e * NTAG + i], c);
    }
    kk[s * EMB + e] = a;
    vv[s * EMB + e] = c;
  }
}

// ---------------------------------------------------------------------------
// Attention: 4 (tb,head) units per 256-thread block. S=14 keys, HD=128.
// ---------------------------------------------------------------------------
__global__ __launch_bounds__(256) void attn_kernel(
    const bf16* __restrict__ q, const float* __restrict__ kk,
    const float* __restrict__ vv, bf16* __restrict__ ao)
{
  const int unit = blockIdx.x * 4 + (threadIdx.x >> 6);
  const int h = unit & 7;
  const int tb = unit >> 3;
  const int lane = threadIdx.x & 63;
  const size_t qbase = (size_t)tb * EMB + h * 128;
  const int kbase = h * 128 + lane;
  float q0 = __bfloat162float(q[qbase + lane]);
  float q1 = __bfloat162float(q[qbase + 64 + lane]);
  float sc[NTAG];
#pragma unroll
  for (int j = 0; j < NTAG; ++j) {
    float p = q0 * kk[j * EMB + kbase] + q1 * kk[j * EMB + 64 + kbase];
#pragma unroll
    for (int d = 32; d; d >>= 1) p += __shfl_xor(p, d);
    sc[j] = p * 0.088388347648318447f;  // 1/sqrt(128)
  }
  float m = sc[0];
#pragma unroll
  for (int j = 1; j < NTAG; ++j) m = fmaxf(m, sc[j]);
  float sum = 0.f;
#pragma unroll
  for (int j = 0; j < NTAG; ++j) { sc[j] = expf(sc[j] - m); sum += sc[j]; }
  float inv = 1.f / sum;
  float o0 = 0.f, o1 = 0.f;
#pragma unroll
  for (int j = 0; j < NTAG; ++j) {
    float p = sc[j] * inv;
    o0 = fmaf(p, vv[j * EMB + kbase], o0);
    o1 = fmaf(p, vv[j * EMB + 64 + kbase], o1);
  }
  ao[qbase + lane] = __float2bfloat16(o0);
  ao[qbase + 64 + lane] = __float2bfloat16(o1);
}

// ---------------------------------------------------------------------------
// Fused final linear + ne-table logits: 4 (t,b) units per block.
// ---------------------------------------------------------------------------
__global__ __launch_bounds__(256) void dec_logits_kernel(
    const bf16* __restrict__ dec, const float* __restrict__ lin_w,
    const float* __restrict__ lin_b, const float* __restrict__ ne,
    float* __restrict__ logits)
{
  const int tb = blockIdx.x * 4 + (threadIdx.x >> 6);
  const int t = tb >> 6;
  const int b = tb & 63;
  const int lane = threadIdx.x & 63;
  const bf16* drow = dec + (size_t)tb * EMB;
  float dv[16];
#pragma unroll
  for (int i = 0; i < 16; ++i) dv[i] = __bfloat162float(drow[lane + 64 * i]);
  float dl[NTAG];
#pragma unroll
  for (int n = 0; n < NTAG; ++n) {
    float p = 0.f;
#pragma unroll
    for (int i = 0; i < 16; ++i)
      p = fmaf(dv[i], lin_w[n * EMB + lane + 64 * i], p);
#pragma unroll
    for (int d = 32; d; d >>= 1) p += __shfl_xor(p, d);
    dl[n] = p + lin_b[n];
  }
  if (lane < NTAG) {
    float acc = 0.f;
#pragma unroll
    for (int d2 = 0; d2 < NTAG; ++d2)
      acc = fmaf(dl[d2], ne[lane * NTAG + d2], acc);
    logits[((size_t)b * T_SEQ + t) * NTAG + lane] = acc * 0.26726124191242439f; // 1/sqrt(14)
  }
}

// ---------------------------------------------------------------------------
// CRF NLL per batch element (one wave per b; alpha recurrence over T).
// ---------------------------------------------------------------------------
__global__ __launch_bounds__(64) void crf_kernel(
    const float* __restrict__ logits, const int* __restrict__ labels,
    const float* __restrict__ cstart, const float* __restrict__ cend,
    const float* __restrict__ ctrans, float* __restrict__ lossb)
{
  const int b = blockIdx.x;
  const int lane = threadIdx.x;
  __shared__ float al[NTAG];
  __shared__ float tr[NTAG * NTAG];
  __shared__ float tmp[NTAG];
  const float* lg = logits + (size_t)b * T_SEQ * NTAG;
  const int* lab = labels + (size_t)b * T_SEQ;
  for (int i = lane; i < NTAG * NTAG; i += 64) tr[i] = ctrans[i];
  if (lane < NTAG) al[lane] = cstart[lane] + lg[lane];
  __syncthreads();
  for (int t = 1; t < T_SEQ; ++t) {
    float v = 0.f;
    if (lane < NTAG) {
      float mx = -1e30f;
#pragma unroll
      for (int i = 0; i < NTAG; ++i) mx = fmaxf(mx, al[i] + tr[i * NTAG + lane]);
      float sm = 0.f;
#pragma unroll
      for (int i = 0; i < NTAG; ++i) sm += expf(al[i] + tr[i * NTAG + lane] - mx);
      v = mx + logf(sm) + lg[t * NTAG + lane];
    }
    __syncthreads();
    if (lane < NTAG) al[lane] = v;
    __syncthreads();
  }
  float em = 0.f;
  for (int t = lane; t < T_SEQ; t += 64) em += lg[t * NTAG + lab[t]];
  float trs = 0.f;
  for (int t = lane; t < T_SEQ - 1; t += 64) trs += tr[lab[t] * NTAG + lab[t + 1]];
  float p = em + trs;
#pragma unroll
  for (int d = 32; d; d >>= 1) p += __shfl_xor(p, d);
  if (lane < NTAG) tmp[lane] = al[lane] + cend[lane];
  __syncthreads();
  if (lane == 0) {
    float num = p + cstart[lab[0]] + cend[lab[T_SEQ - 1]];
    float mx = tmp[0];
#pragma unroll
    for (int i = 1; i < NTAG; ++i) mx = fmaxf(mx, tmp[i]);
    float sm = 0.f;
#pragma unroll
    for (int i = 0; i < NTAG; ++i) sm += expf(tmp[i] - mx);
    float den = mx + logf(sm);
    lossb[b] = -(num - den);
  }
}

__global__ __launch_bounds__(64) void final_reduce(
    const float* __restrict__ lossb, float* __restrict__ out)
{
  float v = lossb[threadIdx.x];
#pragma unroll
  for (int d = 32; d; d >>= 1) v += __shfl_xor(v, d);
  if (threadIdx.x == 0) out[0] = v * (1.f / 64.f);
}

// ---------------------------------------------------------------------------
extern "C" void kernel_launch(void* const* d_in, const int* in_sizes, int n_in,
                              void* d_out, int out_size, void* d_ws, size_t ws_size,
                              hipStream_t stream)
{
  const float* features = (const float*)d_in[0];
  const int*   labels   = (const int*)d_in[1];
  const float* ne_table = (const float*)d_in[2];
  const float* g1_wih_f = (const float*)d_in[3];
  const float* g1_whh_f = (const float*)d_in[4];
  const float* g1_bih_f = (const float*)d_in[5];
  const float* g1_bhh_f = (const float*)d_in[6];
  const float* g1_wih_b = (const float*)d_in[7];
  const float* g1_whh_b = (const float*)d_in[8];
  const float* g1_bih_b = (const float*)d_in[9];
  const float* g1_bhh_b = (const float*)d_in[10];
  const float* g2_wih_f = (const float*)d_in[11];
  const float* g2_whh_f = (const float*)d_in[12];
  const float* g2_bih_f = (const float*)d_in[13];
  const float* g2_bhh_f = (const float*)d_in[14];
  const float* g2_wih_b = (const float*)d_in[15];
  const float* g2_whh_b = (const float*)d_in[16];
  const float* g2_bih_b = (const float*)d_in[17];
  const float* g2_bhh_b = (const float*)d_in[18];
  const float* q_w   = (const float*)d_in[19];
  const float* q_b   = (const float*)d_in[20];
  const float* k_w   = (const float*)d_in[21];
  const float* k_b   = (const float*)d_in[22];
  const float* v_w   = (const float*)d_in[23];
  const float* v_b   = (const float*)d_in[24];
  const float* out_w = (const float*)d_in[25];
  const float* out_b = (const float*)d_in[26];
  const float* lin_w = (const float*)d_in[27];
  const float* lin_b = (const float*)d_in[28];
  const float* crf_start = (const float*)d_in[29];
  const float* crf_end   = (const float*)d_in[30];
  const float* crf_trans = (const float*)d_in[31];

  // ---- workspace layout (~219 MB) ----
  const size_t NTB = (size_t)T_SEQ * BATCH;      // 16384
  char* base = (char*)d_ws;
  size_t off = 0;
  auto alloc = [&](size_t bytes) {
    char* p = base + off;
    off += (bytes + 255) & ~(size_t)255;
    return p;
  };
  bf16* xpA  = (bf16*)alloc(NTB * G3 * sizeof(bf16));   // xp fwd (gru1, then gru2)
  bf16* xpB  = (bf16*)alloc(NTB * G3 * sizeof(bf16));   // xp bwd
  bf16* enc  = (bf16*)alloc(NTB * EMB * sizeof(bf16));  // gru1 output
  bf16* bufD = (bf16*)alloc(NTB * EMB * sizeof(bf16));  // xT -> aoraw -> dec
  bf16* bufE = (bf16*)alloc(NTB * EMB * sizeof(bf16));  // q -> aofin
  float* kkbuf  = (float*)alloc((size_t)NTAG * EMB * sizeof(float));
  float* vvbuf  = (float*)alloc((size_t)NTAG * EMB * sizeof(float));
  float* logits = (float*)alloc(NTB * NTAG * sizeof(float));
  float* lossb  = (float*)alloc(64 * sizeof(float));
  int*   flags  = (int*)alloc(2 * FLAG_LAYER * sizeof(int)); // layer1, layer2
  // bf16 weight copies (~24.3 MB; layer-1 w_ih padded to FPAD)
  bf16* w1if = (bf16*)alloc((size_t)G3 * FPAD * sizeof(bf16));
  bf16* w1ib = (bf16*)alloc((size_t)G3 * FPAD * sizeof(bf16));
  bf16* w1hf = (bf16*)alloc((size_t)G3 * HID * sizeof(bf16));
  bf16* w1hb = (bf16*)alloc((size_t)G3 * HID * sizeof(bf16));
  bf16* w2if = (bf16*)alloc((size_t)G3 * 2 * EMB * sizeof(bf16));
  bf16* w2ib = (bf16*)alloc((size_t)G3 * 2 * EMB * sizeof(bf16));
  bf16* w2hf = (bf16*)alloc((size_t)G3 * HID * sizeof(bf16));
  bf16* w2hb = (bf16*)alloc((size_t)G3 * HID * sizeof(bf16));
  bf16* wq   = (bf16*)alloc((size_t)EMB * EMB * sizeof(bf16));
  bf16* wo   = (bf16*)alloc((size_t)EMB * EMB * sizeof(bf16));
  (void)off; (void)ws_size; (void)in_sizes; (void)n_in; (void)out_size;

  bf16* xT = bufD;  // [T,B,FPAD] bf16, aliases bufD (dead before aoraw)

  const int M = (int)NTB;  // 16384
  dim3 blk(256);

  // 0. zero flag regions (each launch -> replay-deterministic)
  hipMemsetAsync(flags, 0, 2 * FLAG_LAYER * sizeof(int), stream);

  // 0b. weight conversions fp32 -> bf16 (layer-1 w_ih zero-padded to FPAD)
  auto conv = [&](const float* s, bf16* d, size_t n) {
    f32_to_bf16<<<(int)((n / 4 + 255) / 256), blk, 0, stream>>>(s, d, (int)(n / 4));
  };
  f32_to_bf16_pad<<<(G3 * FPAD + 255) / 256, blk, 0, stream>>>(g1_wih_f, w1if, G3);
  f32_to_bf16_pad<<<(G3 * FPAD + 255) / 256, blk, 0, stream>>>(g1_wih_b, w1ib, G3);
  conv(g1_whh_f, w1hf, (size_t)G3 * HID);
  conv(g1_whh_b, w1hb, (size_t)G3 * HID);
  conv(g2_wih_f, w2if, (size_t)G3 * 2 * EMB);
  conv(g2_wih_b, w2ib, (size_t)G3 * 2 * EMB);
  conv(g2_whh_f, w2hf, (size_t)G3 * HID);
  conv(g2_whh_b, w2hb, (size_t)G3 * HID);
  conv(q_w, wq, (size_t)EMB * EMB);
  conv(out_w, wo, (size_t)EMB * EMB);

  // 1. features -> [T,B,FPAD] bf16 (zero-padded)
  transpose_feat<<<(BATCH * T_SEQ * FPAD + 255) / 256, blk, 0, stream>>>(features, xT);

  dim3 g_xp(G3 / 128, M / 128);   // (12,128)
  dim3 g_e(EMB / 128, M / 128);   // (8,128)

  // 2. GRU1 input projections (K padded to 192)
  gemm_mfma<<<g_xp, blk, 0, stream>>>(xT, FPAD, nullptr, 0, FPAD,
                                      w1if, FPAD, g1_bih_f, xpA, G3, M, G3, FPAD);
  gemm_mfma<<<g_xp, blk, 0, stream>>>(xT, FPAD, nullptr, 0, FPAD,
                                      w1ib, FPAD, g1_bih_b, xpB, G3, M, G3, FPAD);

  // 3. GRU1 recurrence -> enc (per-wave chains, 64 blocks)
  gru_persist<<<GRU_NBLK, blk, 0, stream>>>(xpA, xpB, w1hf, w1hb,
                                            g1_bhh_f, g1_bhh_b, enc, flags);

  // 4. K/V (batch-independent) + Q projection -> bufE
  kv_kernel<<<4, blk, 0, stream>>>(ne_table, k_w, k_b, v_w, v_b, kkbuf, vvbuf);
  gemm_mfma<<<g_e, blk, 0, stream>>>(enc, EMB, nullptr, 0, EMB,
                                     wq, EMB, q_b, bufE, EMB, M, EMB, EMB);

  // 5. Attention (q=bufE -> aoraw=bufD) + output projection (-> aofin=bufE)
  attn_kernel<<<M * 2, blk, 0, stream>>>(bufE, kkbuf, vvbuf, bufD);
  gemm_mfma<<<g_e, blk, 0, stream>>>(bufD, EMB, nullptr, 0, EMB,
                                     wo, EMB, out_b, bufE, EMB, M, EMB, EMB);

  // 6. GRU2 input projections: dec_in = [enc, ao] via concat-A GEMM
  gemm_mfma<<<g_xp, blk, 0, stream>>>(enc, EMB, bufE, EMB, EMB,
                                      w2if, 2 * EMB, g2_bih_f, xpA, G3, M, G3, 2 * EMB);
  gemm_mfma<<<g_xp, blk, 0, stream>>>(enc, EMB, bufE, EMB, EMB,
                                      w2ib, 2 * EMB, g2_bih_b, xpB, G3, M, G3, 2 * EMB);

  // 7. GRU2 recurrence -> dec (bufD; aoraw dead)
  gru_persist<<<GRU_NBLK, blk, 0, stream>>>(xpA, xpB, w2hf, w2hb,
                                            g2_bhh_f, g2_bhh_b, bufD,
                                            flags + FLAG_LAYER);

  // 8. Final linear + ne logits
  dec_logits_kernel<<<M / 4, blk, 0, stream>>>(bufD, lin_w, lin_b, ne_table, logits);

  // 9. CRF NLL + mean
  crf_kernel<<<BATCH, 64, 0, stream>>>(logits, labels, crf_start, crf_end, crf_trans, lossb);
  final_reduce<<<1, 64, 0, stream>>>(lossb, (float*)d_out);
}

// Round 18
// 4138.992 us; speedup vs baseline: 1.3165x; 1.0030x over previous
//
#include <hip/hip_runtime.h>
#include <hip/hip_bf16.h>
#include <math.h>

typedef __hip_bfloat16 bf16;
typedef __bf16 bf16x8 __attribute__((ext_vector_type(8)));
typedef float  f32x4  __attribute__((ext_vector_type(4)));
typedef unsigned long long u64;
typedef unsigned int u32;

#define T_SEQ 256
#define BATCH 64
#define FEATD 188
#define FPAD  192    // FEATD zero-padded to 16B-friendly multiple of 32
#define HID   512
#define EMB   1024
#define NTAG  14
#define G3    1536   // 3*HID
#define GRU_NBLK 64  // 32 blocks/dir x 16 hidden cols
#define FLAG_LAYER (8 * T_SEQ * 32)   // ints/layer: (dir*4+wave) x step x 32 producers

// ---------------------------------------------------------------------------
// fp32 -> bf16 weight conversion (vectorized x4; all n % 4 == 0)
// ---------------------------------------------------------------------------
__global__ __launch_bounds__(256) void f32_to_bf16(
    const float* __restrict__ src, bf16* __restrict__ dst, int n4)
{
  int i = blockIdx.x * 256 + threadIdx.x;
  if (i >= n4) return;
  float4 v = *(const float4*)(src + (size_t)i * 4);
  bf16 o[4] = {__float2bfloat16(v.x), __float2bfloat16(v.y),
               __float2bfloat16(v.z), __float2bfloat16(v.w)};
  *(ushort4*)(dst + (size_t)i * 4) = *(ushort4*)o;
}

// fp32 [rows x 188] -> bf16 [rows x 192] zero-padded
__global__ __launch_bounds__(256) void f32_to_bf16_pad(
    const float* __restrict__ src, bf16* __restrict__ dst, int rows)
{
  int idx = blockIdx.x * 256 + threadIdx.x;
  int total = rows * FPAD;
  if (idx >= total) return;
  int r = idx / FPAD, i = idx - r * FPAD;
  float v = (i < FEATD) ? src[(size_t)r * FEATD + i] : 0.f;
  dst[idx] = __float2bfloat16(v);
}

// ---------------------------------------------------------------------------
// MFMA GEMM v14: dual-output. C{1,2}[M,N{1,2}] = concat(A1,A2)[M,K] @ W{1,2}^T
// + bias{1,2}. Blocks bx < n1b compute output set 1, the rest set 2 (same A
// panel -> A fetched once per dispatch). m97-style global_load_lds staging
// (linear LDS, width=16). Packed u32 C-stores via lane-pair shfl.
// All K multiples of 32; all row strides multiples of 16B.
// ---------------------------------------------------------------------------
__global__ __launch_bounds__(256) void gemm_mfma(
    const bf16* __restrict__ A1, int lda1,
    const bf16* __restrict__ A2, int lda2, int K1,
    const bf16* __restrict__ W1, const float* __restrict__ bias1,
    bf16* __restrict__ C1, int ldc1, int n1b,
    const bf16* __restrict__ W2, const float* __restrict__ bias2,
    bf16* __restrict__ C2, int ldc2,
    int ldw, int M, int K)
{
  __shared__ __align__(16) __bf16 As[128 * 32];
  __shared__ __align__(16) __bf16 Bs[128 * 32];
  const int bx = blockIdx.x;
  const int set2 = (bx >= n1b);
  const bf16* W = set2 ? W2 : W1;
  const float* bias = set2 ? bias2 : bias1;
  bf16* C = set2 ? C2 : C1;
  const int ldc = set2 ? ldc2 : ldc1;
  const int bn = (set2 ? (bx - n1b) : bx) * 128;
  const int bm = blockIdx.y * 128;
  const int tid = threadIdx.x;
  const int wave = tid >> 6, lane = tid & 63;
  const int wr = wave >> 1, wc = wave & 1;
  const int lr = lane & 15, lk = (lane >> 4) << 3;
  const int srow = wave * 16 + (lane >> 2);
  const int scol = (lane & 3) * 8;
  f32x4 acc[4][4] = {};
  for (int k0 = 0; k0 < K; k0 += 32) {
#pragma unroll
    for (int j = 0; j < 2; ++j) {
      const int row = srow + j * 64;
      const int kg = k0 + scol;
      const bf16* srca = (kg < K1) ? A1 + (size_t)(bm + row) * lda1 + kg
                                   : A2 + (size_t)(bm + row) * lda2 + (kg - K1);
      const bf16* srcb = W + (size_t)(bn + row) * ldw + kg;
      __builtin_amdgcn_global_load_lds(
          (const __attribute__((address_space(1))) u32*)srca,
          (__attribute__((address_space(3))) u32*)(&As[j * 2048 + wave * 512]),
          16, 0, 0);
      __builtin_amdgcn_global_load_lds(
          (const __attribute__((address_space(1))) u32*)srcb,
          (__attribute__((address_space(3))) u32*)(&Bs[j * 2048 + wave * 512]),
          16, 0, 0);
    }
    __syncthreads();   // drains vmcnt (incl. global_load_lds) before barrier
    bf16x8 af[4], bf_[4];
#pragma unroll
    for (int i = 0; i < 4; ++i)
      af[i] = *(const bf16x8*)&As[(wr * 64 + i * 16 + lr) * 32 + lk];
#pragma unroll
    for (int j = 0; j < 4; ++j)
      bf_[j] = *(const bf16x8*)&Bs[(wc * 64 + j * 16 + lr) * 32 + lk];
#pragma unroll
    for (int i = 0; i < 4; ++i)
#pragma unroll
      for (int j = 0; j < 4; ++j)
        acc[i][j] = __builtin_amdgcn_mfma_f32_16x16x32_bf16(af[i], bf_[j], acc[i][j], 0, 0, 0);
    __syncthreads();
  }
#pragma unroll
  for (int j = 0; j < 4; ++j) {
    int n = bn + wc * 64 + j * 16 + lr;
    float bv = bias ? bias[n] : 0.f;
#pragma unroll
    for (int i = 0; i < 4; ++i) {
#pragma unroll
      for (int p = 0; p < 4; ++p) {
        int m = bm + wr * 64 + i * 16 + (lane >> 4) * 4 + p;
        bf16 hv = __float2bfloat16(acc[i][j][p] + bv);
        int mb = *(unsigned short*)&hv;
        int pb = __shfl_xor(mb, 1);
        if (!(lr & 1)) {
          u32 pk = (u32)mb | ((u32)pb << 16);
          *(u32*)(C + (size_t)m * ldc + n) = pk;
        }
      }
    }
  }
}

// ---------------------------------------------------------------------------
// features [B,T,FEAT] fp32 -> xT [T,B,FPAD] bf16 (zero-padded)
// ---------------------------------------------------------------------------
__global__ __launch_bounds__(256) void transpose_feat(
    const float* __restrict__ f, bf16* __restrict__ xT)
{
  const int idx = blockIdx.x * 256 + threadIdx.x;
  const int total = BATCH * T_SEQ * FPAD;
  if (idx >= total) return;
  const int i = idx % FPAD;
  const int r = idx / FPAD;
  const int t = r / BATCH;
  const int b = r % BATCH;
  float v = (i < FEATD) ? f[((size_t)b * T_SEQ + t) * FEATD + i] : 0.f;
  xT[idx] = __float2bfloat16(v);
}

// ---------------------------------------------------------------------------
// Persistent bidirectional GRU layer (R16 verbatim; best 1690us).
// 64 blocks (dir x 32 col-tiles of 16 cols), 256 threads = 4 waves.
// Per-(dir,wave) chains, 32 producer flags/step, drain -> flag -> xp
// prefetch, zero __syncthreads in the loop.
// ---------------------------------------------------------------------------
__global__ __launch_bounds__(256, 1) void gru_persist(
    const bf16* __restrict__ xp_f, const bf16* __restrict__ xp_b,
    const bf16* __restrict__ whh_f, const bf16* __restrict__ whh_b,
    const float* __restrict__ bhh_f, const float* __restrict__ bhh_b,
    bf16* __restrict__ out, int* __restrict__ flags)
{
  const int blk = blockIdx.x;
  const int dir = blk >> 5;
  const int ct  = blk & 31;
  const bf16* xp   = dir ? xp_b  : xp_f;
  const bf16* whh  = dir ? whh_b : whh_f;
  const float* bhh = dir ? bhh_b : bhh_f;
  const int off = dir ? HID : 0;
  const int tid = threadIdx.x;
  const int wave = tid >> 6, lane = tid & 63;
  const int lr = lane & 15, lkq = lane >> 4;
  int* fl = flags + (size_t)(dir * 4 + wave) * (T_SEQ * 32);

  __shared__ __bf16 Ws[48][520];
  for (int i = tid; i < 48 * 64; i += 256) {
    int r = i >> 6, q = i & 63;
    int grow = (r >> 4) * HID + ct * 16 + (r & 15);
    *(float4*)&Ws[r][q * 8] = *(const float4*)(whh + (size_t)grow * HID + q * 8);
  }
  __syncthreads();   // ONLY block-wide sync; before the loop.

  float bh[3];
#pragma unroll
  for (int g = 0; g < 3; ++g)
    bh[g] = bhh[g * HID + ct * 16 + lr];

  float hp[4] = {};

  bf16 xc[3][4];
  {
    const int t0 = dir ? (T_SEQ - 1) : 0;
    const size_t xb = (size_t)t0 * BATCH * G3;
#pragma unroll
    for (int p = 0; p < 4; ++p) {
      const size_t xrow = xb + (size_t)(wave * 16 + lkq * 4 + p) * G3;
#pragma unroll
      for (int g = 0; g < 3; ++g)
        xc[g][p] = xp[xrow + g * HID + ct * 16 + lr];
    }
  }

  for (int s = 0; s < T_SEQ; ++s) {
    const int t = dir ? (T_SEQ - 1 - s) : s;

    f32x4 acc[3] = {};
    if (s > 0) {
      int ready = 0;
      do {
        int f = 1;
        if (lane < 32)
          f = __hip_atomic_load(&fl[(s - 1) * 32 + lane],
                                __ATOMIC_RELAXED, __HIP_MEMORY_SCOPE_AGENT);
        ready = __all(f != 0);
        if (!ready) __builtin_amdgcn_s_sleep(1);
      } while (!ready);
      __builtin_amdgcn_sched_barrier(0);
      const int tp = dir ? t + 1 : t - 1;
      const bf16* arow = out + (size_t)tp * BATCH * EMB + off
                         + (size_t)(wave * 16 + lr) * EMB + lkq * 8;
      u64 h0[16], h1[16];
#pragma unroll
      for (int ki = 0; ki < 16; ++ki) {
        h0[ki] = __hip_atomic_load((const u64*)(arow + ki * 32),
                                   __ATOMIC_RELAXED, __HIP_MEMORY_SCOPE_AGENT);
        h1[ki] = __hip_atomic_load((const u64*)(arow + ki * 32 + 4),
                                   __ATOMIC_RELAXED, __HIP_MEMORY_SCOPE_AGENT);
      }
#pragma unroll
      for (int ki = 0; ki < 16; ++ki) {
        union { u64 v[2]; bf16x8 f; } ua;
        ua.v[0] = h0[ki]; ua.v[1] = h1[ki];
#pragma unroll
        for (int g = 0; g < 3; ++g) {
          bf16x8 b = *(const bf16x8*)&Ws[g * 16 + lr][ki * 32 + lkq * 8];
          acc[g] = __builtin_amdgcn_mfma_f32_16x16x32_bf16(ua.f, b, acc[g], 0, 0, 0);
        }
      }
    }

    const size_t obase = (size_t)t * BATCH * EMB + off;
    const int c = ct * 16 + lr;
#pragma unroll
    for (int p = 0; p < 4; ++p) {
      const int m = wave * 16 + lkq * 4 + p;
      float xr = __bfloat162float(xc[0][p]);
      float xz = __bfloat162float(xc[1][p]);
      float xn = __bfloat162float(xc[2][p]);
      float r = 1.f / (1.f + expf(-(xr + acc[0][p] + bh[0])));
      float z = 1.f / (1.f + expf(-(xz + acc[1][p] + bh[1])));
      float n = tanhf(xn + r * (acc[2][p] + bh[2]));
      float h = (1.f - z) * n + z * hp[p];
      hp[p] = h;
      bf16 hvb = __float2bfloat16(h);
      int mb = *(unsigned short*)&hvb;
      int pb = __shfl_xor(mb, 1);
      if (!(lr & 1)) {
        unsigned int pk = (unsigned int)mb | ((unsigned int)pb << 16);
        __hip_atomic_store((unsigned int*)(out + obase + (size_t)m * EMB + c), pk,
                           __ATOMIC_RELAXED, __HIP_MEMORY_SCOPE_AGENT);
      }
    }

    asm volatile("s_waitcnt vmcnt(0)" ::: "memory");
    if (s + 1 < T_SEQ) {
      if (lane == 0)
        __hip_atomic_store(&fl[s * 32 + ct], 1,
                           __ATOMIC_RELAXED, __HIP_MEMORY_SCOPE_AGENT);
      const int tn = dir ? (T_SEQ - 2 - s) : (s + 1);
      const size_t xb2 = (size_t)tn * BATCH * G3;
#pragma unroll
      for (int p = 0; p < 4; ++p) {
        const size_t xrow = xb2 + (size_t)(wave * 16 + lkq * 4 + p) * G3;
#pragma unroll
        for (int g = 0; g < 3; ++g)
          xc[g][p] = xp[xrow + g * HID + ct * 16 + lr];
      }
    }
  }
}

// ---------------------------------------------------------------------------
// K/V projections: ne batch-broadcast -> K/V collapse to [NT, EMB] fp32.
// ---------------------------------------------------------------------------
__global__ __launch_bounds__(256) void kv_kernel(
    const float* __restrict__ ne, const float* __restrict__ k_w,
    const float* __restrict__ k_b, const float* __restrict__ v_w,
    const float* __restrict__ v_b, float* __restrict__ kk,
    float* __restrict__ vv)
{
  const int e = blockIdx.x * 256 + threadIdx.x;
  if (e >= EMB) return;
#pragma unroll
  for (int s = 0; s < NTAG; ++s) {
    float a = k_b[e], c = v_b[e];
#pragma unroll
    for (int i = 0; i < NTAG; ++i) {
      float nv = ne[s * NTAG + i];
      a = fmaf(nv, k_w[e * NTAG + i], a);
      c = fmaf(nv, v_w[e * NTAG + i], c);
    }
    kk[s * EMB + e] = a;
    vv[s * EMB + e] = c;
  }
}

// ---------------------------------------------------------------------------
// Attention: 4 (tb,head) units per 256-thread block. S=14 keys, HD=128.
// ---------------------------------------------------------------------------
__global__ __launch_bounds__(256) void attn_kernel(
    const bf16* __restrict__ q, const float* __restrict__ kk,
    const float* __restrict__ vv, bf16* __restrict__ ao)
{
  const int unit = blockIdx.x * 4 + (threadIdx.x >> 6);
  const int h = unit & 7;
  const int tb = unit >> 3;
  const int lane = threadIdx.x & 63;
  const size_t qbase = (size_t)tb * EMB + h * 128;
  const int kbase = h * 128 + lane;
  float q0 = __bfloat162float(q[qbase + lane]);
  float q1 = __bfloat162float(q[qbase + 64 + lane]);
  float sc[NTAG];
#pragma unroll
  for (int j = 0; j < NTAG; ++j) {
    float p = q0 * kk[j * EMB + kbase] + q1 * kk[j * EMB + 64 + kbase];
#pragma unroll
    for (int d = 32; d; d >>= 1) p += __shfl_xor(p, d);
    sc[j] = p * 0.088388347648318447f;  // 1/sqrt(128)
  }
  float m = sc[0];
#pragma unroll
  for (int j = 1; j < NTAG; ++j) m = fmaxf(m, sc[j]);
  float sum = 0.f;
#pragma unroll
  for (int j = 0; j < NTAG; ++j) { sc[j] = expf(sc[j] - m); sum += sc[j]; }
  float inv = 1.f / sum;
  float o0 = 0.f, o1 = 0.f;
#pragma unroll
  for (int j = 0; j < NTAG; ++j) {
    float p = sc[j] * inv;
    o0 = fmaf(p, vv[j * EMB + kbase], o0);
    o1 = fmaf(p, vv[j * EMB + 64 + kbase], o1);
  }
  ao[qbase + lane] = __float2bfloat16(o0);
  ao[qbase + 64 + lane] = __float2bfloat16(o1);
}

// ---------------------------------------------------------------------------
// Fused final linear + ne-table logits: 4 (t,b) units per block.
// ---------------------------------------------------------------------------
__global__ __launch_bounds__(256) void dec_logits_kernel(
    const bf16* __restrict__ dec, const float* __restrict__ lin_w,
    const float* __restrict__ lin_b, const float* __restrict__ ne,
    float* __restrict__ logits)
{
  const int tb = blockIdx.x * 4 + (threadIdx.x >> 6);
  const int t = tb >> 6;
  const int b = tb & 63;
  const int lane = threadIdx.x & 63;
  const bf16* drow = dec + (size_t)tb * EMB;
  float dv[16];
#pragma unroll
  for (int i = 0; i < 16; ++i) dv[i] = __bfloat162float(drow[lane + 64 * i]);
  float dl[NTAG];
#pragma unroll
  for (int n = 0; n < NTAG; ++n) {
    float p = 0.f;
#pragma unroll
    for (int i = 0; i < 16; ++i)
      p = fmaf(dv[i], lin_w[n * EMB + lane + 64 * i], p);
#pragma unroll
    for (int d = 32; d; d >>= 1) p += __shfl_xor(p, d);
    dl[n] = p + lin_b[n];
  }
  if (lane < NTAG) {
    float acc = 0.f;
#pragma unroll
    for (int d2 = 0; d2 < NTAG; ++d2)
      acc = fmaf(dl[d2], ne[lane * NTAG + d2], acc);
    logits[((size_t)b * T_SEQ + t) * NTAG + lane] = acc * 0.26726124191242439f; // 1/sqrt(14)
  }
}

// ---------------------------------------------------------------------------
// CRF NLL per batch element (one wave per b; alpha recurrence over T).
// ---------------------------------------------------------------------------
__global__ __launch_bounds__(64) void crf_kernel(
    const float* __restrict__ logits, const int* __restrict__ labels,
    const float* __restrict__ cstart, const float* __restrict__ cend,
    const float* __restrict__ ctrans, float* __restrict__ lossb)
{
  const int b = blockIdx.x;
  const int lane = threadIdx.x;
  __shared__ float al[NTAG];
  __shared__ float tr[NTAG * NTAG];
  __shared__ float tmp[NTAG];
  const float* lg = logits + (size_t)b * T_SEQ * NTAG;
  const int* lab = labels + (size_t)b * T_SEQ;
  for (int i = lane; i < NTAG * NTAG; i += 64) tr[i] = ctrans[i];
  if (lane < NTAG) al[lane] = cstart[lane] + lg[lane];
  __syncthreads();
  for (int t = 1; t < T_SEQ; ++t) {
    float v = 0.f;
    if (lane < NTAG) {
      float mx = -1e30f;
#pragma unroll
      for (int i = 0; i < NTAG; ++i) mx = fmaxf(mx, al[i] + tr[i * NTAG + lane]);
      float sm = 0.f;
#pragma unroll
      for (int i = 0; i < NTAG; ++i) sm += expf(al[i] + tr[i * NTAG + lane] - mx);
      v = mx + logf(sm) + lg[t * NTAG + lane];
    }
    __syncthreads();
    if (lane < NTAG) al[lane] = v;
    __syncthreads();
  }
  float em = 0.f;
  for (int t = lane; t < T_SEQ; t += 64) em += lg[t * NTAG + lab[t]];
  float trs = 0.f;
  for (int t = lane; t < T_SEQ - 1; t += 64) trs += tr[lab[t] * NTAG + lab[t + 1]];
  float p = em + trs;
#pragma unroll
  for (int d = 32; d; d >>= 1) p += __shfl_xor(p, d);
  if (lane < NTAG) tmp[lane] = al[lane] + cend[lane];
  __syncthreads();
  if (lane == 0) {
    float num = p + cstart[lab[0]] + cend[lab[T_SEQ - 1]];
    float mx = tmp[0];
#pragma unroll
    for (int i = 1; i < NTAG; ++i) mx = fmaxf(mx, tmp[i]);
    float sm = 0.f;
#pragma unroll
    for (int i = 0; i < NTAG; ++i) sm += expf(tmp[i] - mx);
    float den = mx + logf(sm);
    lossb[b] = -(num - den);
  }
}

__global__ __launch_bounds__(64) void final_reduce(
    const float* __restrict__ lossb, float* __restrict__ out)
{
  float v = lossb[threadIdx.x];
#pragma unroll
  for (int d = 32; d; d >>= 1) v += __shfl_xor(v, d);
  if (threadIdx.x == 0) out[0] = v * (1.f / 64.f);
}

// ---------------------------------------------------------------------------
extern "C" void kernel_launch(void* const* d_in, const int* in_sizes, int n_in,
                              void* d_out, int out_size, void* d_ws, size_t ws_size,
                              hipStream_t stream)
{
  const float* features = (const float*)d_in[0];
  const int*   labels   = (const int*)d_in[1];
  const float* ne_table = (const float*)d_in[2];
  const float* g1_wih_f = (const float*)d_in[3];
  const float* g1_whh_f = (const float*)d_in[4];
  const float* g1_bih_f = (const float*)d_in[5];
  const float* g1_bhh_f = (const float*)d_in[6];
  const float* g1_wih_b = (const float*)d_in[7];
  const float* g1_whh_b = (const float*)d_in[8];
  const float* g1_bih_b = (const float*)d_in[9];
  const float* g1_bhh_b = (const float*)d_in[10];
  const float* g2_wih_f = (const float*)d_in[11];
  const float* g2_whh_f = (const float*)d_in[12];
  const float* g2_bih_f = (const float*)d_in[13];
  const float* g2_bhh_f = (const float*)d_in[14];
  const float* g2_wih_b = (const float*)d_in[15];
  const float* g2_whh_b = (const float*)d_in[16];
  const float* g2_bih_b = (const float*)d_in[17];
  const float* g2_bhh_b = (const float*)d_in[18];
  const float* q_w   = (const float*)d_in[19];
  const float* q_b   = (const float*)d_in[20];
  const float* k_w   = (const float*)d_in[21];
  const float* k_b   = (const float*)d_in[22];
  const float* v_w   = (const float*)d_in[23];
  const float* v_b   = (const float*)d_in[24];
  const float* out_w = (const float*)d_in[25];
  const float* out_b = (const float*)d_in[26];
  const float* lin_w = (const float*)d_in[27];
  const float* lin_b = (const float*)d_in[28];
  const float* crf_start = (const float*)d_in[29];
  const float* crf_end   = (const float*)d_in[30];
  const float* crf_trans = (const float*)d_in[31];

  // ---- workspace layout (~219 MB) ----
  const size_t NTB = (size_t)T_SEQ * BATCH;      // 16384
  char* base = (char*)d_ws;
  size_t off = 0;
  auto alloc = [&](size_t bytes) {
    char* p = base + off;
    off += (bytes + 255) & ~(size_t)255;
    return p;
  };
  bf16* xpA  = (bf16*)alloc(NTB * G3 * sizeof(bf16));   // xp fwd (gru1, then gru2)
  bf16* xpB  = (bf16*)alloc(NTB * G3 * sizeof(bf16));   // xp bwd
  bf16* enc  = (bf16*)alloc(NTB * EMB * sizeof(bf16));  // gru1 output
  bf16* bufD = (bf16*)alloc(NTB * EMB * sizeof(bf16));  // xT -> aoraw -> dec
  bf16* bufE = (bf16*)alloc(NTB * EMB * sizeof(bf16));  // q -> aofin
  float* kkbuf  = (float*)alloc((size_t)NTAG * EMB * sizeof(float));
  float* vvbuf  = (float*)alloc((size_t)NTAG * EMB * sizeof(float));
  float* logits = (float*)alloc(NTB * NTAG * sizeof(float));
  float* lossb  = (float*)alloc(64 * sizeof(float));
  int*   flags  = (int*)alloc(2 * FLAG_LAYER * sizeof(int)); // layer1, layer2
  // bf16 weight copies (~24.3 MB; layer-1 w_ih padded to FPAD)
  bf16* w1if = (bf16*)alloc((size_t)G3 * FPAD * sizeof(bf16));
  bf16* w1ib = (bf16*)alloc((size_t)G3 * FPAD * sizeof(bf16));
  bf16* w1hf = (bf16*)alloc((size_t)G3 * HID * sizeof(bf16));
  bf16* w1hb = (bf16*)alloc((size_t)G3 * HID * sizeof(bf16));
  bf16* w2if = (bf16*)alloc((size_t)G3 * 2 * EMB * sizeof(bf16));
  bf16* w2ib = (bf16*)alloc((size_t)G3 * 2 * EMB * sizeof(bf16));
  bf16* w2hf = (bf16*)alloc((size_t)G3 * HID * sizeof(bf16));
  bf16* w2hb = (bf16*)alloc((size_t)G3 * HID * sizeof(bf16));
  bf16* wq   = (bf16*)alloc((size_t)EMB * EMB * sizeof(bf16));
  bf16* wo   = (bf16*)alloc((size_t)EMB * EMB * sizeof(bf16));
  (void)off; (void)ws_size; (void)in_sizes; (void)n_in; (void)out_size;

  bf16* xT = bufD;  // [T,B,FPAD] bf16, aliases bufD (dead before aoraw)

  const int M = (int)NTB;  // 16384
  dim3 blk(256);

  // 0. zero flag regions (each launch -> replay-deterministic)
  hipMemsetAsync(flags, 0, 2 * FLAG_LAYER * sizeof(int), stream);

  // 0b. weight conversions fp32 -> bf16 (layer-1 w_ih zero-padded to FPAD)
  auto conv = [&](const float* s, bf16* d, size_t n) {
    f32_to_bf16<<<(int)((n / 4 + 255) / 256), blk, 0, stream>>>(s, d, (int)(n / 4));
  };
  f32_to_bf16_pad<<<(G3 * FPAD + 255) / 256, blk, 0, stream>>>(g1_wih_f, w1if, G3);
  f32_to_bf16_pad<<<(G3 * FPAD + 255) / 256, blk, 0, stream>>>(g1_wih_b, w1ib, G3);
  conv(g1_whh_f, w1hf, (size_t)G3 * HID);
  conv(g1_whh_b, w1hb, (size_t)G3 * HID);
  conv(g2_wih_f, w2if, (size_t)G3 * 2 * EMB);
  conv(g2_wih_b, w2ib, (size_t)G3 * 2 * EMB);
  conv(g2_whh_f, w2hf, (size_t)G3 * HID);
  conv(g2_whh_b, w2hb, (size_t)G3 * HID);
  conv(q_w, wq, (size_t)EMB * EMB);
  conv(out_w, wo, (size_t)EMB * EMB);

  // 1. features -> [T,B,FPAD] bf16 (zero-padded)
  transpose_feat<<<(BATCH * T_SEQ * FPAD + 255) / 256, blk, 0, stream>>>(features, xT);

  // 2. GRU1 input projections f+b FUSED (one dispatch, shared A panel)
  gemm_mfma<<<dim3(2 * G3 / 128, M / 128), blk, 0, stream>>>(
      xT, FPAD, nullptr, 0, FPAD,
      w1if, g1_bih_f, xpA, G3, G3 / 128,
      w1ib, g1_bih_b, xpB, G3,
      FPAD, M, FPAD);

  // 3. GRU1 recurrence -> enc (per-wave chains, 64 blocks)
  gru_persist<<<GRU_NBLK, blk, 0, stream>>>(xpA, xpB, w1hf, w1hb,
                                            g1_bhh_f, g1_bhh_b, enc, flags);

  // 4. K/V (batch-independent) + Q projection -> bufE
  kv_kernel<<<4, blk, 0, stream>>>(ne_table, k_w, k_b, v_w, v_b, kkbuf, vvbuf);
  gemm_mfma<<<dim3(EMB / 128, M / 128), blk, 0, stream>>>(
      enc, EMB, nullptr, 0, EMB,
      wq, q_b, bufE, EMB, EMB / 128,
      nullptr, nullptr, nullptr, 0,
      EMB, M, EMB);

  // 5. Attention (q=bufE -> aoraw=bufD) + output projection (-> aofin=bufE)
  attn_kernel<<<M * 2, blk, 0, stream>>>(bufE, kkbuf, vvbuf, bufD);
  gemm_mfma<<<dim3(EMB / 128, M / 128), blk, 0, stream>>>(
      bufD, EMB, nullptr, 0, EMB,
      wo, out_b, bufE, EMB, EMB / 128,
      nullptr, nullptr, nullptr, 0,
      EMB, M, EMB);

  // 6. GRU2 input projections f+b FUSED: dec_in = [enc, ao] concat-A
  gemm_mfma<<<dim3(2 * G3 / 128, M / 128), blk, 0, stream>>>(
      enc, EMB, bufE, EMB, EMB,
      w2if, g2_bih_f, xpA, G3, G3 / 128,
      w2ib, g2_bih_b, xpB, G3,
      2 * EMB, M, 2 * EMB);

  // 7. GRU2 recurrence -> dec (bufD; aoraw dead)
  gru_persist<<<GRU_NBLK, blk, 0, stream>>>(xpA, xpB, w2hf, w2hb,
                                            g2_bhh_f, g2_bhh_b, bufD,
                                            flags + FLAG_LAYER);

  // 8. Final linear + ne logits
  dec_logits_kernel<<<M / 4, blk, 0, stream>>>(bufD, lin_w, lin_b, ne_table, logits);

  // 9. CRF NLL + mean
  crf_kernel<<<BATCH, 64, 0, stream>>>(logits, labels, crf_start, crf_end, crf_trans, lossb);
  final_reduce<<<1, 64, 0, stream>>>(lossb, (float*)d_out);
}